// Round 19
// baseline (135.353 us; speedup 1.0000x reference)
//
#include <hip/hip_runtime.h>

// EncoderLayer: pre-norm MHA + FFN, B=2 S=2048 D=768 H=12 DFF=2048, fp32 I/O,
// bf16 MFMA internals. Pipeline:
//   pre (weights->bf16 + bias concat + LN1), QKV-GEMM(fused, Q pre-scaled, 128x128),
//   flash-attn (pipelined: QK(i+1) || softmax+PV(i); tr-read V, ones-MFMA row-sum),
//   Wo-GEMM+res (64x64 dbuf), LN2, FFN1+relu (64x128), FFN2+res (64x64 dbuf) -> d_out
// GEMM LDS tiles XOR-swizzled (attn-K pattern): 0 bank conflicts on ds_read_b128.
// 64x64 GEMMs double-buffered (T3-minimum 2-phase): 1 barrier/K-step, staging
// overlaps compute.
#define SS   2048
#define DD   768
#define HH   12
#define DFFF 2048
#define BSR  4096      // B*S
#define QKV_LD 2304

typedef __attribute__((ext_vector_type(8))) short bf16x8;
typedef __attribute__((ext_vector_type(4))) float f32x4;

__device__ __forceinline__ unsigned short f2b(float f) {
  union { float f; unsigned u; } x; x.f = f;
  unsigned r = (x.u + 0x7FFFu + ((x.u >> 16) & 1u)) >> 16;
  return (unsigned short)r;
}

__device__ __forceinline__ unsigned cvtpk(float lo, float hi) {
  unsigned r;
  asm("v_cvt_pk_bf16_f32 %0, %1, %2" : "=v"(r) : "v"(lo), "v"(hi));
  return r;
}

__device__ __forceinline__ void gload_lds16(const void* g, void* l) {
  __builtin_amdgcn_global_load_lds(
      (const __attribute__((address_space(1))) unsigned int*)g,
      (__attribute__((address_space(3))) unsigned int*)l,
      16, 0, 0);
}

// low 32 bits of a flat __shared__ pointer = LDS byte offset on gfx9
__device__ __forceinline__ unsigned lds_u32(const void* p) {
  return (unsigned)(unsigned long long)p;
}

// ---------------- LayerNorm row (torch semantics: ddof=1, eps on std) -------
__device__ __forceinline__ void ln_row(const float* __restrict__ xr,
                                       const float* __restrict__ alpha,
                                       const float* __restrict__ beta,
                                       unsigned short* __restrict__ orow, int lane) {
  float4 v[3];
#pragma unroll
  for (int g = 0; g < 3; ++g) v[g] = *(const float4*)&xr[lane * 12 + g * 4];
  float sum = 0.f;
#pragma unroll
  for (int g = 0; g < 3; ++g) sum += v[g].x + v[g].y + v[g].z + v[g].w;
#pragma unroll
  for (int off = 1; off < 64; off <<= 1) sum += __shfl_xor(sum, off);
  float mu = sum * (1.0f / 768.0f);
  float ss = 0.f;
#pragma unroll
  for (int g = 0; g < 3; ++g) {
    float a0 = v[g].x - mu, a1 = v[g].y - mu, a2 = v[g].z - mu, a3 = v[g].w - mu;
    ss += a0 * a0 + a1 * a1 + a2 * a2 + a3 * a3;
  }
#pragma unroll
  for (int off = 1; off < 64; off <<= 1) ss += __shfl_xor(ss, off);
  float sd = sqrtf(ss * (1.0f / 767.0f));
  float inv = 1.0f / (sd + 1e-6f);
#pragma unroll
  for (int g = 0; g < 3; ++g) {
    float4 al = *(const float4*)&alpha[lane * 12 + g * 4];
    float4 be = *(const float4*)&beta[lane * 12 + g * 4];
    uint2 pk;
    pk.x = cvtpk(al.x * (v[g].x - mu) * inv + be.x, al.y * (v[g].y - mu) * inv + be.y);
    pk.y = cvtpk(al.z * (v[g].z - mu) * inv + be.z, al.w * (v[g].w - mu) * inv + be.w);
    *(uint2*)&orow[lane * 12 + g * 4] = pk;
  }
}

// ------- merged: weight fp32->bf16 + bias concat + LN1 (one launch) ---------
__global__ __launch_bounds__(256) void pre_k(const float* __restrict__ Wq,
                                             const float* __restrict__ Wk,
                                             const float* __restrict__ Wv,
                                             const float* __restrict__ Wo,
                                             const float* __restrict__ W1,
                                             const float* __restrict__ W2,
                                             const float* __restrict__ bq,
                                             const float* __restrict__ bk,
                                             const float* __restrict__ bv,
                                             const float* __restrict__ x,
                                             const float* __restrict__ alpha,
                                             const float* __restrict__ beta,
                                             unsigned short* __restrict__ wqkv,
                                             unsigned short* __restrict__ wo_b,
                                             unsigned short* __restrict__ w1_b,
                                             unsigned short* __restrict__ w2_b,
                                             float* __restrict__ bqkv,
                                             unsigned short* __restrict__ n_b) {
  const int blk = blockIdx.x;
  const float* src;
  unsigned short* dst;
  long off;
  if (blk < 1728) {            // Wq/Wk/Wv -> wqkv rows [0,2304)
    int r = blk / 576;
    src = r == 0 ? Wq : r == 1 ? Wk : Wv;
    dst = wqkv + (long)r * 589824;
    off = (long)(blk - r * 576) * 1024 + threadIdx.x * 4;
  } else if (blk < 2304) {
    src = Wo; dst = wo_b; off = (long)(blk - 1728) * 1024 + threadIdx.x * 4;
  } else if (blk < 3840) {
    src = W1; dst = w1_b; off = (long)(blk - 2304) * 1024 + threadIdx.x * 4;
  } else if (blk < 5376) {
    src = W2; dst = w2_b; off = (long)(blk - 3840) * 1024 + threadIdx.x * 4;
  } else if (blk == 5376) {    // bias concat
    for (int k = threadIdx.x; k < 2304; k += 256)
      bqkv[k] = k < 768 ? bq[k] : k < 1536 ? bk[k - 768] : bv[k - 1536];
    return;
  } else {                     // LN1: 4 rows per block
    int row = (blk - 5377) * 4 + (threadIdx.x >> 6);
    ln_row(x + (long)row * DD, alpha, beta, n_b + (long)row * DD, threadIdx.x & 63);
    return;
  }
  float4 v = *(const float4*)&src[off];
  uint2 pk;
  pk.x = cvtpk(v.x, v.y);
  pk.y = cvtpk(v.z, v.w);
  *(uint2*)&dst[off] = pk;
}

// ---------------- LN2 standalone ----------------
__global__ __launch_bounds__(256) void layernorm_k(const float* __restrict__ x,
                                                   const float* __restrict__ alpha,
                                                   const float* __restrict__ beta,
                                                   unsigned short* __restrict__ outb) {
  int row = blockIdx.x * 4 + (threadIdx.x >> 6);
  ln_row(x + (long)row * DD, alpha, beta, outb + (long)row * DD, threadIdx.x & 63);
}

// ---------------- bf16 GEMM: C[M,N] = A[M,K] * W[N,K]^T (+bias,+res,relu) ----
// BMxBN tile, BK=64, 4 waves (2x2), global_load_lds staging.
// LDS XOR-swizzle (attn-K proven pattern): stage source col chunk ^= row&7
// (linear LDS dest), fragment reads offset ^= (l15&7)<<4 -> conflict-free.
// DBUF (64x64 only): double LDS buffer, COMPUTE(k); barrier; STAGE(k+2) --
// one barrier/K-step, staging overlaps compute (T3-minimum 2-phase).
// XCD-chunked block swizzle (requires (gridDim.x*gridDim.y) % 8 == 0).
// QSC: scale cols<768 by 0.125*log2(e) (Q pre-scale for exp2-domain attn).
template <int BM, int BN, bool RELU, bool RES, bool OUTB, bool QSC, bool DBUF>
__global__ __launch_bounds__(256, (BM == 64 || BN == 64) ? 4 : 3)
void gemm_bt(const unsigned short* __restrict__ A,
             const unsigned short* __restrict__ W,
             const float* __restrict__ bias,
             const float* __restrict__ res,
             void* __restrict__ outp,
             int M, int N, int K) {
  constexpr int NBUF = DBUF ? 2 : 1;
  __shared__ __align__(16) unsigned short As[NBUF][BM * 64];
  __shared__ __align__(16) unsigned short Bs[NBUF][BN * 64];
  constexpr int MF = BM / 32;   // 16-wide row frags per wave
  constexpr int NF = BN / 32;   // 16-wide col frags per wave
  const int t = threadIdx.x;
  const int lane = t & 63;
  const int w = t >> 6;
  const int wr = w >> 1, wc = w & 1;
  const int l15 = lane & 15, l4 = lane >> 4;
  // XCD-chunked swizzle: contiguous chunk of blocks (sharing A-panels) per XCD
  const int nwg = gridDim.x * gridDim.y;
  const int lin = blockIdx.y * gridDim.x + blockIdx.x;
  const int u2 = (lin & 7) * (nwg >> 3) + (lin >> 3);
  const long brow = (long)(u2 / gridDim.x) * BM;
  const long bcol = (long)(u2 % gridDim.x) * BN;
  f32x4 acc[MF][NF] = {};
  const int r0 = t >> 3;                       // 0..31 (row within 32-chunk)
  const int c8s = (((t & 7) ^ (r0 & 7)) & 7) * 8;  // swizzled col (shorts)
  const int rd_swz = (l15 & 7) << 4;           // read-side XOR (bytes)

#define G_STAGE(ab, bb, k0)                                                     \
  { _Pragma("unroll") for (int p = 0; p < BM / 32; ++p)                         \
      gload_lds16(&A[(brow + p * 32 + r0) * (long)K + (k0) + c8s],              \
                  (char*)(ab) + p * 4096 + w * 1024);                           \
    _Pragma("unroll") for (int p = 0; p < BN / 32; ++p)                         \
      gload_lds16(&W[(bcol + p * 32 + r0) * (long)K + (k0) + c8s],              \
                  (char*)(bb) + p * 4096 + w * 1024); }

#define G_COMPUTE(ab, bb)                                                       \
  { _Pragma("unroll") for (int ks = 0; ks < 2; ++ks) {                          \
      bf16x8 a[MF], b[NF];                                                      \
      _Pragma("unroll") for (int m = 0; m < MF; ++m)                            \
        a[m] = *(const bf16x8*)((const char*)(ab) +                             \
                                (wr * (BM / 2) + m * 16 + l15) * 128 +          \
                                ((ks * 64 + l4 * 16) ^ rd_swz));                \
      _Pragma("unroll") for (int n = 0; n < NF; ++n)                            \
        b[n] = *(const bf16x8*)((const char*)(bb) +                             \
                                (wc * (BN / 2) + n * 16 + l15) * 128 +          \
                                ((ks * 64 + l4 * 16) ^ rd_swz));                \
      _Pragma("unroll") for (int m = 0; m < MF; ++m)                            \
      _Pragma("unroll") for (int n = 0; n < NF; ++n)                            \
        acc[m][n] = __builtin_amdgcn_mfma_f32_16x16x32_bf16(a[m], b[n],         \
                                                            acc[m][n], 0, 0, 0); \
    } }

  if constexpr (DBUF) {
    // prologue: stage tile0, drain, issue stage tile1
    G_STAGE(As[0], Bs[0], 0);
    __syncthreads();
    G_STAGE(As[1], Bs[1], 64);
    int kb = 0;
    for (int k0 = 0;; k0 += 64, kb ^= 1) {
      G_COMPUTE(As[kb], Bs[kb]);
      if (k0 + 64 >= K) break;
      __syncthreads();            // drains stage(k0+64); reads of buf kb done
      if (k0 + 128 < K) G_STAGE(As[kb], Bs[kb], k0 + 128);
    }
  } else {
    for (int k0 = 0; k0 < K; k0 += 64) {
      __syncthreads();
      G_STAGE(As[0], Bs[0], k0);
      __syncthreads();
      G_COMPUTE(As[0], Bs[0]);
    }
  }
#undef G_STAGE
#undef G_COMPUTE

#pragma unroll
  for (int n = 0; n < NF; ++n) {
    const long col = bcol + wc * (BN / 2) + n * 16 + l15;
    const float bv = bias[col];
    const float sc = (QSC && col < 768) ? 0.18033688f : 1.0f;
#pragma unroll
    for (int m = 0; m < MF; ++m) {
      const long row0 = brow + wr * (BM / 2) + m * 16 + l4 * 4;
#pragma unroll
      for (int r = 0; r < 4; ++r) {
        float v = acc[m][n][r] + bv;
        if (RELU) v = fmaxf(v, 0.0f);
        if (QSC) v *= sc;
        long o = (row0 + r) * (long)N + col;
        if (RES) v += res[o];
        if (OUTB) ((unsigned short*)outp)[o] = f2b(v);
        else ((float*)outp)[o] = v;
      }
    }
  }
}

// ---------------- flash attention v13: pipelined QK(i+1) || softmax+PV(i) ---
// One block per (b,h,64-q-tile), grid 768, 256 threads, 4 waves, 32 KV tiles.
// K: 2 LDS buffers; V: 3 LDS buffers (stage 2 tiles ahead; per-iteration
// writers {K[i&1], V[(i+2)%3]} disjoint from readers {K[(i+1)&1], V[i%3]}).
// tr-read V path, ones-MFMA row-sum, exp2 softmax, defer-max, cvt_pk.
// LDS 40 KB x 4 blocks = 160 KiB exactly -> declare 4 blocks/CU.
__global__ __launch_bounds__(256, 4) void attn_kernel(const unsigned short* __restrict__ qkv,
                                                      const int* __restrict__ mask,
                                                      unsigned short* __restrict__ ctx) {
  __shared__ __align__(16) unsigned short Ks[2][64 * 64];  // K [key][d], XOR-swz
  __shared__ __align__(16) unsigned short Vt[3][64 * 64];  // V subtiled for tr-read
  const int t = threadIdx.x, lane = t & 63, w = t >> 6;
  const int l15 = lane & 15, l4 = lane >> 4;
  // XCD-chunked swizzle (768 % 8 == 0, bijective)
  const int u = (blockIdx.x & 7) * 96 + (blockIdx.x >> 3);
  const int qt = u & 31;
  const int h = (u >> 5) % 12;
  const int b = u / 384;
  const long rowB = (long)b * SS;

  // ---- mask bitmap (scratch aliased onto Vt[0]; staged only later) ----
  unsigned bm;
  {
    int* tfl = (int*)&Vt[0][0];
    const int* mb = &mask[b * SS + t * 8];
    int4 a0 = *(const int4*)mb;
    int4 a1 = *(const int4*)(mb + 4);
    int allv = (a0.x && a0.y && a0.z && a0.w && a1.x && a1.y && a1.z && a1.w) ? 1 : 0;
    allv &= __shfl_xor(allv, 1);
    allv &= __shfl_xor(allv, 2);
    allv &= __shfl_xor(allv, 4);
    if ((t & 7) == 0) tfl[t >> 3] = allv;
    __syncthreads();
    int vv = (lane < 32) ? tfl[lane] : 1;
    bm = (unsigned)__ballot(vv);   // per-wave; bit kb = tile kb fully unmasked
    __syncthreads();               // scratch dead before Vt[0] is staged
  }

  // Q fragment (B operand): lane l15 = q, elems d = ks*32 + l4*8 + j
  bf16x8 aq[2];
#pragma unroll
  for (int ks = 0; ks < 2; ++ks)
    aq[ks] = *(const bf16x8*)&qkv[(rowB + qt * 64 + w * 16 + l15) * QKV_LD +
                                  h * 64 + ks * 32 + l4 * 8];

  // K staging (gload_lds linear dest; XOR swizzle folded into global src col)
  const int krow = w * 8 + (lane >> 3);                          // +p*32
  const int kdo = (((lane & 7) ^ (lane >> 3)) & 7) << 3;         // shorts
  const unsigned short* kgbase = &qkv[(rowB + krow) * QKV_LD + 768 + h * 64 + kdo];
  const int kread_swz = (l15 & 7) << 4;

  // V staging: decode linear dest X = p*4096 + w*1024 + lane*16 into (key, d0)
  const unsigned short* vsrc[2];
#pragma unroll
  for (int p = 0; p < 2; ++p) {
    int X = p * 4096 + w * 1024 + lane * 16;
    int d_blk = X >> 11;
    int rem = X & 2047;
    int k_blk = rem >> 7;
    int krw = (rem >> 5) & 3;
    int c = (rem >> 4) & 1;
    int vkey = k_blk * 4 + krw;
    int vd0 = d_blk * 16 + c * 8;
    vsrc[p] = &qkv[(rowB + vkey) * QKV_LD + 1536 + h * 64 + vd0];
  }
  // tr-read per-lane address part; rotating V read bases (i%3: 0,1,2,...)
  const unsigned vtrl = (unsigned)(l15 * 2 + l4 * 128);
  unsigned vad0 = lds_u32(&Vt[0][0]) + vtrl;
  unsigned vad1 = lds_u32(&Vt[1][0]) + vtrl;
  unsigned vad2 = lds_u32(&Vt[2][0]) + vtrl;
  // rotating V stage-dest bases ((i+2)%3: 2,0,1,...)
  char* vdst0 = (char*)&Vt[2][0];
  char* vdst1 = (char*)&Vt[0][0];
  char* vdst2 = (char*)&Vt[1][0];
  // K read/stage bases (QK(i+1) reads parity (i+1)&1; stage(i+2) -> parity i&1)
  const char* kread = (const char*)&Ks[1][0];
  char* kdst = (char*)&Ks[0][0];

  // ones A-operand for row-sum MFMA (bf16 1.0 = 0x3F80)
  union { unsigned uu[4]; bf16x8 b8; } vone;
  vone.uu[0] = vone.uu[1] = vone.uu[2] = vone.uu[3] = 0x3F803F80u;

  f32x4 o[4] = {};
  f32x4 o4 = {};                 // row-sum accumulator (all regs = sum for q=l15)
  float mrun = -1e30f;
  f32x4 sp[4];                   // scores of tile i (being softmaxed/PV'd)

#define QK_INTO(dst, kbase)                                                     \
  { __builtin_amdgcn_s_setprio(1);                                             \
    _Pragma("unroll") for (int ks = 0; ks < 2; ++ks)                           \
    _Pragma("unroll") for (int cg = 0; cg < 4; ++cg) {                         \
      bf16x8 ak = *(const bf16x8*)((kbase) + (cg * 16 + l15) * 128 +           \
                                   ((ks * 64 + l4 * 16) ^ kread_swz));         \
      dst[cg] = __builtin_amdgcn_mfma_f32_16x16x32_bf16(ak, aq[ks], dst[cg], 0, 0, 0); \
    }                                                                           \
    __builtin_amdgcn_s_setprio(0); }

#define MASK_APPLY(dst, kb)                                                     \
  if (__builtin_expect(!((bm >> (kb)) & 1), 0)) {                              \
    const int* mb2 = &mask[b * SS + (kb) * 64 + l4 * 4];                       \
    _Pragma("unroll") for (int cg = 0; cg < 4; ++cg) {                         \
      int4 mm = *(const int4*)(mb2 + cg * 16);                                 \
      int mi[4] = {mm.x, mm.y, mm.z, mm.w};                                    \
      _Pragma("unroll") for (int r = 0; r < 4; ++r)                            \
        dst[cg][r] += mi[r] ? 0.f : -1.44269504e9f;                            \
    } }

  // ---- prologue: stage tile 0, drain, issue stage tile 1, QK(0) ----
#pragma unroll
  for (int p = 0; p < 2; ++p)
    gload_lds16(kgbase + (long)p * 32 * QKV_LD, (char*)&Ks[0][0] + p * 4096 + w * 1024);
#pragma unroll
  for (int p = 0; p < 2; ++p)
    gload_lds16(vsrc[p], (char*)&Vt[0][0] + p * 4096 + w * 1024);
  __syncthreads();
#pragma unroll
  for (int p = 0; p < 2; ++p)
    gload_lds16(kgbase + ((long)64 + p * 32) * QKV_LD, (char*)&Ks[1][0] + p * 4096 + w * 1024);
#pragma unroll
  for (int p = 0; p < 2; ++p)
    gload_lds16(vsrc[p] + (long)64 * QKV_LD, (char*)&Vt[1][0] + p * 4096 + w * 1024);
#pragma unroll
  for (int cg = 0; cg < 4; ++cg) sp[cg] = f32x4{0.f, 0.f, 0.f, 0.f};
  QK_INTO(sp, (const char*)&Ks[0][0]);
  MASK_APPLY(sp, 0);

  for (int i = 0; i < 31; ++i) {
    __syncthreads();   // stage(i+1) landed; all QK(i) reads of Ks done
    // ---- issue stage(i+2): K -> kdst (parity i&1), V -> vdst0 ((i+2)%3) ----
    if (i < 30) {
#pragma unroll
      for (int p = 0; p < 2; ++p)
        gload_lds16(kgbase + ((long)(i + 2) * 64 + p * 32) * QKV_LD,
                    kdst + p * 4096 + w * 1024);
#pragma unroll
      for (int p = 0; p < 2; ++p)
        gload_lds16(vsrc[p] + (long)(i + 2) * 64 * QKV_LD,
                    vdst0 + p * 4096 + w * 1024);
    }
    // ---- QK(i+1) from kread (MFMA pipe; overlaps softmax(i) below) ----
    f32x4 sc[4] = {};
    QK_INTO(sc, kread);
    MASK_APPLY(sc, i + 1);
    // ---- softmax(i) on sp (exp2 domain, per-q stats, q=l15) ----
    {
      float t0 = fmaxf(fmaxf(sp[0][0], sp[0][1]), sp[0][2]);
      float t1 = fmaxf(fmaxf(sp[0][3], sp[1][0]), sp[1][1]);
      float t2 = fmaxf(fmaxf(sp[1][2], sp[1][3]), sp[2][0]);
      float t3 = fmaxf(fmaxf(sp[2][1], sp[2][2]), sp[2][3]);
      float t4 = fmaxf(fmaxf(sp[3][0], sp[3][1]), sp[3][2]);
      float t5 = fmaxf(fmaxf(t0, t1), t2);
      float t6 = fmaxf(fmaxf(t3, t4), sp[3][3]);
      float pmax = fmaxf(t5, t6);
      pmax = fmaxf(pmax, __shfl_xor(pmax, 16));
      pmax = fmaxf(pmax, __shfl_xor(pmax, 32));
      if (!__all(pmax <= mrun + 8.0f)) {   // defer-max (THR=8, exp2 domain)
        float mnew = fmaxf(mrun, pmax);
        float fac = __builtin_amdgcn_exp2f(mrun - mnew);
#pragma unroll
        for (int mg = 0; mg < 4; ++mg)
#pragma unroll
          for (int r = 0; r < 4; ++r) o[mg][r] *= fac;
#pragma unroll
        for (int r = 0; r < 4; ++r) o4[r] *= fac;
        mrun = mnew;
      }
#pragma unroll
      for (int cg = 0; cg < 4; ++cg)
#pragma unroll
        for (int r = 0; r < 4; ++r)
          sp[cg][r] = __builtin_amdgcn_exp2f(sp[cg][r] - mrun);
    }
    // ---- PV(i): bp from sp, av via tr-reads of V[i%3] (vad0) ----
    __builtin_amdgcn_s_setprio(1);
#pragma unroll
    for (int ks = 0; ks < 2; ++ks) {
      union { unsigned uu[4]; bf16x8 b8; } bp;
      bp.uu[0] = cvtpk(sp[2 * ks][0], sp[2 * ks][1]);
      bp.uu[1] = cvtpk(sp[2 * ks][2], sp[2 * ks][3]);
      bp.uu[2] = cvtpk(sp[2 * ks + 1][0], sp[2 * ks + 1][1]);
      bp.uu[3] = cvtpk(sp[2 * ks + 1][2], sp[2 * ks + 1][3]);
      uint2 q0, q1, q2, q3, q4, q5, q6, q7;
      if (ks == 0) {
        asm volatile(
            "ds_read_b64_tr_b16 %0, %8 offset:0\n\t"
            "ds_read_b64_tr_b16 %1, %8 offset:512\n\t"
            "ds_read_b64_tr_b16 %2, %8 offset:2048\n\t"
            "ds_read_b64_tr_b16 %3, %8 offset:2560\n\t"
            "ds_read_b64_tr_b16 %4, %8 offset:4096\n\t"
            "ds_read_b64_tr_b16 %5, %8 offset:4608\n\t"
            "ds_read_b64_tr_b16 %6, %8 offset:6144\n\t"
            "ds_read_b64_tr_b16 %7, %8 offset:6656\n\t"
            "s_waitcnt lgkmcnt(0)"
            : "=&v"(q0), "=&v"(q1), "=&v"(q2), "=&v"(q3),
              "=&v"(q4), "=&v"(q5), "=&v"(q6), "=&v"(q7)
            : "v"(vad0));
      } else {
        asm volatile(
            "ds_read_b64_tr_b16 %0, %8 offset:1024\n\t"
            "ds_read_b64_tr_b16 %1, %8 offset:1536\n\t"
            "ds_read_b64_tr_b16 %2, %8 offset:3072\n\t"
            "ds_read_b64_tr_b16 %3, %8 offset:3584\n\t"
            "ds_read_b64_tr_b16 %4, %8 offset:5120\n\t"
            "ds_read_b64_tr_b16 %5, %8 offset:5632\n\t"
            "ds_read_b64_tr_b16 %6, %8 offset:7168\n\t"
            "ds_read_b64_tr_b16 %7, %8 offset:7680\n\t"
            "s_waitcnt lgkmcnt(0)"
            : "=&v"(q0), "=&v"(q1), "=&v"(q2), "=&v"(q3),
              "=&v"(q4), "=&v"(q5), "=&v"(q6), "=&v"(q7)
            : "v"(vad0));
      }
      union { uint2 u2[2]; bf16x8 b8; } av0, av1, av2, av3;
      av0.u2[0] = q0; av0.u2[1] = q1;
      av1.u2[0] = q2; av1.u2[1] = q3;
      av2.u2[0] = q4; av2.u2[1] = q5;
      av3.u2[0] = q6; av3.u2[1] = q7;
      o[0] = __builtin_amdgcn_mfma_f32_16x16x32_bf16(av0.b8, bp.b8, o[0], 0, 0, 0);
      o[1] = __builtin_amdgcn_mfma_f32_16x16x32_bf16(av1.b8, bp.b8, o[1], 0, 0, 0);
      o[2] = __builtin_amdgcn_mfma_f32_16x16x32_bf16(av2.b8, bp.b8, o[2], 0, 0, 0);
      o[3] = __builtin_amdgcn_mfma_f32_16x16x32_bf16(av3.b8, bp.b8, o[3], 0, 0, 0);
      o4 = __builtin_amdgcn_mfma_f32_16x16x32_bf16(vone.b8, bp.b8, o4, 0, 0, 0);
    }
    __builtin_amdgcn_s_setprio(0);
    // ---- rotate: sp <- sc; swap K bases; rotate V bases ----
#pragma unroll
    for (int cg = 0; cg < 4; ++cg) sp[cg] = sc[cg];
    { const char* tk = kread; kread = kdst; kdst = (char*)tk; }
    { unsigned tv = vad0; vad0 = vad1; vad1 = vad2; vad2 = tv; }
    { char* td = vdst0; vdst0 = vdst1; vdst1 = vdst2; vdst2 = td; }
  }

  // ---- epilogue tile 31: softmax(31) on sp + PV(31) from vad0 (Vt[1]) ----
  {
    float t0 = fmaxf(fmaxf(sp[0][0], sp[0][1]), sp[0][2]);
    float t1 = fmaxf(fmaxf(sp[0][3], sp[1][0]), sp[1][1]);
    float t2 = fmaxf(fmaxf(sp[1][2], sp[1][3]), sp[2][0]);
    float t3 = fmaxf(fmaxf(sp[2][1], sp[2][2]), sp[2][3]);
    float t4 = fmaxf(fmaxf(sp[3][0], sp[3][1]), sp[3][2]);
    float t5 = fmaxf(fmaxf(t0, t1), t2);
    float t6 = fmaxf(fmaxf(t3, t4), sp[3][3]);
    float pmax = fmaxf(t5, t6);
    pmax = fmaxf(pmax, __shfl_xor(pmax, 16));
    pmax = fmaxf(pmax, __shfl_xor(pmax, 32));
    if (!__all(pmax <= mrun + 8.0f)) {
      float mnew = fmaxf(mrun, pmax);
      float fac = __builtin_amdgcn_exp2f(mrun - mnew);
#pragma unroll
      for (int mg = 0; mg < 4; ++mg)
#pragma unroll
        for (int r = 0; r < 4; ++r) o[mg][r] *= fac;
#pragma unroll
      for (int r = 0; r < 4; ++r) o4[r] *= fac;
      mrun = mnew;
    }
#pragma unroll
    for (int cg = 0; cg < 4; ++cg)
#pragma unroll
      for (int r = 0; r < 4; ++r)
        sp[cg][r] = __builtin_amdgcn_exp2f(sp[cg][r] - mrun);
#pragma unroll
    for (int ks = 0; ks < 2; ++ks) {
      union { unsigned uu[4]; bf16x8 b8; } bp;
      bp.uu[0] = cvtpk(sp[2 * ks][0], sp[2 * ks][1]);
      bp.uu[1] = cvtpk(sp[2 * ks][2], sp[2 * ks][3]);
      bp.uu[2] = cvtpk(sp[2 * ks + 1][0], sp[2 * ks + 1][1]);
      bp.uu[3] = cvtpk(sp[2 * ks + 1][2], sp[2 * ks + 1][3]);
      uint2 q0, q1, q2, q3, q4, q5, q6, q7;
      if (ks == 0) {
        asm volatile(
            "ds_read_b64_tr_b16 %0, %8 offset:0\n\t"
            "ds_read_b64_tr_b16 %1, %8 offset:512\n\t"
            "ds_read_b64_tr_b16 %2, %8 offset:2048\n\t"
            "ds_read_b64_tr_b16 %3, %8 offset:2560\n\t"
            "ds_read_b64_tr_b16 %4, %8 offset:4096\n\t"
            "ds_read_b64_tr_b16 %5, %8 offset:4608\n\t"
            "ds_read_b64_tr_b16 %6, %8 offset:6144\n\t"
            "ds_read_b64_tr_b16 %7, %8 offset:6656\n\t"
            "s_waitcnt lgkmcnt(0)"
            : "=&v"(q0), "=&v"(q1), "=&v"(q2), "=&v"(q3),
              "=&v"(q4), "=&v"(q5), "=&v"(q6), "=&v"(q7)
            : "v"(vad0));
      } else {
        asm volatile(
            "ds_read_b64_tr_b16 %0, %8 offset:1024\n\t"
            "ds_read_b64_tr_b16 %1, %8 offset:1536\n\t"
            "ds_read_b64_tr_b16 %2, %8 offset:3072\n\t"
            "ds_read_b64_tr_b16 %3, %8 offset:3584\n\t"
            "ds_read_b64_tr_b16 %4, %8 offset:5120\n\t"
            "ds_read_b64_tr_b16 %5, %8 offset:5632\n\t"
            "ds_read_b64_tr_b16 %6, %8 offset:7168\n\t"
            "ds_read_b64_tr_b16 %7, %8 offset:7680\n\t"
            "s_waitcnt lgkmcnt(0)"
            : "=&v"(q0), "=&v"(q1), "=&v"(q2), "=&v"(q3),
              "=&v"(q4), "=&v"(q5), "=&v"(q6), "=&v"(q7)
            : "v"(vad0));
      }
      union { uint2 u2[2]; bf16x8 b8; } av0, av1, av2, av3;
      av0.u2[0] = q0; av0.u2[1] = q1;
      av1.u2[0] = q2; av1.u2[1] = q3;
      av2.u2[0] = q4; av2.u2[1] = q5;
      av3.u2[0] = q6; av3.u2[1] = q7;
      o[0] = __builtin_amdgcn_mfma_f32_16x16x32_bf16(av0.b8, bp.b8, o[0], 0, 0, 0);
      o[1] = __builtin_amdgcn_mfma_f32_16x16x32_bf16(av1.b8, bp.b8, o[1], 0, 0, 0);
      o[2] = __builtin_amdgcn_mfma_f32_16x16x32_bf16(av2.b8, bp.b8, o[2], 0, 0, 0);
      o[3] = __builtin_amdgcn_mfma_f32_16x16x32_bf16(av3.b8, bp.b8, o[3], 0, 0, 0);
      o4 = __builtin_amdgcn_mfma_f32_16x16x32_bf16(vone.b8, bp.b8, o4, 0, 0, 0);
    }
  }
#undef QK_INTO
#undef MASK_APPLY

  // ---- epilogue: O^T regs hold col q=l15, row d=mg*16+l4*4+r; o4 = lsum ----
  const float inv = 1.0f / o4[0];
  const long obase = (rowB + qt * 64 + w * 16 + l15) * DD + h * 64 + l4 * 4;
#pragma unroll
  for (int mg = 0; mg < 4; ++mg) {
    *(unsigned*)&ctx[obase + mg * 16] = cvtpk(o[mg][0] * inv, o[mg][1] * inv);
    *(unsigned*)&ctx[obase + mg * 16 + 2] = cvtpk(o[mg][2] * inv, o[mg][3] * inv);
  }
}

// ---------------- workspace layout (bytes) ----------------
static const size_t OFF_WQKV = 0;          // 2304*768*2  = 3538944
static const size_t OFF_WO = 3538944;      // 768*768*2   = 1179648
static const size_t OFF_W1 = 4718592;      // 2048*768*2  = 3145728
static const size_t OFF_W2 = 7864320;      // 768*2048*2  = 3145728
static const size_t OFF_BQKV = 11010048;   // 2304*4
static const size_t OFF_N = 11019264;      // 4096*768*2  (reused for n2)
static const size_t OFF_QKV = 17310720;    // 4096*2304*2 (reused for h)
static const size_t OFF_CTX = 36185088;    // 4096*768*2
static const size_t OFF_X1 = 42476544;     // 4096*768*4
// total = 55059456 bytes

extern "C" void kernel_launch(void* const* d_in, const int* in_sizes, int n_in,
                              void* d_out, int out_size, void* d_ws, size_t ws_size,
                              hipStream_t stream) {
  (void)in_sizes; (void)n_in; (void)out_size; (void)ws_size;
  const float* x = (const float*)d_in[0];
  const int* mask = (const int*)d_in[1];
  const float* Wq = (const float*)d_in[2];
  const float* bq = (const float*)d_in[3];
  const float* Wk = (const float*)d_in[4];
  const float* bk = (const float*)d_in[5];
  const float* Wv = (const float*)d_in[6];
  const float* bv = (const float*)d_in[7];
  const float* Wo = (const float*)d_in[8];
  const float* bo = (const float*)d_in[9];
  const float* W1 = (const float*)d_in[10];
  const float* b1 = (const float*)d_in[11];
  const float* W2 = (const float*)d_in[12];
  const float* b2 = (const float*)d_in[13];
  const float* alpha = (const float*)d_in[14];
  const float* beta = (const float*)d_in[15];

  char* ws = (char*)d_ws;
  unsigned short* wqkv = (unsigned short*)(ws + OFF_WQKV);
  unsigned short* wo_b = (unsigned short*)(ws + OFF_WO);
  unsigned short* w1_b = (unsigned short*)(ws + OFF_W1);
  unsigned short* w2_b = (unsigned short*)(ws + OFF_W2);
  float* bqkv = (float*)(ws + OFF_BQKV);
  unsigned short* n_b = (unsigned short*)(ws + OFF_N);
  unsigned short* qkv_b = (unsigned short*)(ws + OFF_QKV);
  unsigned short* h_b = qkv_b;  // reuse after attention
  unsigned short* ctx_b = (unsigned short*)(ws + OFF_CTX);
  float* x1_f = (float*)(ws + OFF_X1);
  float* out_f = (float*)d_out;

  // weights->bf16 + bias concat + LN1 in one launch (5377 cvt/bias + 1024 LN)
  pre_k<<<6401, 256, 0, stream>>>(Wq, Wk, Wv, Wo, W1, W2, bq, bk, bv,
                                  x, alpha, beta, wqkv, wo_b, w1_b, w2_b, bqkv, n_b);
  // fused QKV GEMM: [4096,768] x [2304,768]^T -> [4096,2304] bf16, Q pre-scaled
  gemm_bt<128, 128, false, false, true, true, false><<<dim3(18, 32), 256, 0, stream>>>(
      n_b, wqkv, bqkv, nullptr, qkv_b, BSR, QKV_LD, DD);
  // attention: one block per (b,h,qt), full KV, pipelined tr-read V path
  attn_kernel<<<768, 256, 0, stream>>>(qkv_b, mask, ctx_b);
  // Wo GEMM + residual(x) -> x1 fp32 (64x64 dbuf: 768 blocks, 12 barriers)
  gemm_bt<64, 64, false, true, false, false, true><<<dim3(12, 64), 256, 0, stream>>>(
      ctx_b, wo_b, bo, x, x1_f, BSR, DD, DD);
  // LN2
  layernorm_k<<<1024, 256, 0, stream>>>(x1_f, alpha, beta, n_b);
  // FFN1 + relu -> h bf16 (64x128 tiles: 1024 blocks, exactly 4/CU)
  gemm_bt<64, 128, true, false, true, false, false><<<dim3(16, 64), 256, 0, stream>>>(
      n_b, w1_b, b1, nullptr, h_b, BSR, DFFF, DD);
  // FFN2 + residual(x1) -> out fp32 (64x64 dbuf: 768 blocks, 32 barriers)
  gemm_bt<64, 64, false, true, false, false, true><<<dim3(12, 64), 256, 0, stream>>>(
      h_b, w2_b, b2, x1_f, out_f, BSR, DD, DFFF);
}

// Round 20
// 132.882 us; speedup vs baseline: 1.0186x; 1.0186x over previous
//
#include <hip/hip_runtime.h>

// EncoderLayer: pre-norm MHA + FFN, B=2 S=2048 D=768 H=12 DFF=2048, fp32 I/O,
// bf16 MFMA internals. Pipeline:
//   pre (wqkv->bf16 + bias concat + LN1), QKV-GEMM(fused, Q pre-scaled, 128x128),
//   flash-attn (pipelined; + 228 fused blocks converting Wo/W1/W2 under attn),
//   Wo-GEMM+res (64x64), LN2, FFN1+relu (64x128), FFN2+res (64x64) -> d_out
// GEMM LDS tiles XOR-swizzled: 0 bank conflicts on ds_read_b128.
#define SS   2048
#define DD   768
#define HH   12
#define DFFF 2048
#define BSR  4096      // B*S
#define QKV_LD 2304

typedef __attribute__((ext_vector_type(8))) short bf16x8;
typedef __attribute__((ext_vector_type(4))) float f32x4;

__device__ __forceinline__ unsigned short f2b(float f) {
  union { float f; unsigned u; } x; x.f = f;
  unsigned r = (x.u + 0x7FFFu + ((x.u >> 16) & 1u)) >> 16;
  return (unsigned short)r;
}

__device__ __forceinline__ unsigned cvtpk(float lo, float hi) {
  unsigned r;
  asm("v_cvt_pk_bf16_f32 %0, %1, %2" : "=v"(r) : "v"(lo), "v"(hi));
  return r;
}

__device__ __forceinline__ void gload_lds16(const void* g, void* l) {
  __builtin_amdgcn_global_load_lds(
      (const __attribute__((address_space(1))) unsigned int*)g,
      (__attribute__((address_space(3))) unsigned int*)l,
      16, 0, 0);
}

// low 32 bits of a flat __shared__ pointer = LDS byte offset on gfx9
__device__ __forceinline__ unsigned lds_u32(const void* p) {
  return (unsigned)(unsigned long long)p;
}

// ---------------- LayerNorm row (torch semantics: ddof=1, eps on std) -------
__device__ __forceinline__ void ln_row(const float* __restrict__ xr,
                                       const float* __restrict__ alpha,
                                       const float* __restrict__ beta,
                                       unsigned short* __restrict__ orow, int lane) {
  float4 v[3];
#pragma unroll
  for (int g = 0; g < 3; ++g) v[g] = *(const float4*)&xr[lane * 12 + g * 4];
  float sum = 0.f;
#pragma unroll
  for (int g = 0; g < 3; ++g) sum += v[g].x + v[g].y + v[g].z + v[g].w;
#pragma unroll
  for (int off = 1; off < 64; off <<= 1) sum += __shfl_xor(sum, off);
  float mu = sum * (1.0f / 768.0f);
  float ss = 0.f;
#pragma unroll
  for (int g = 0; g < 3; ++g) {
    float a0 = v[g].x - mu, a1 = v[g].y - mu, a2 = v[g].z - mu, a3 = v[g].w - mu;
    ss += a0 * a0 + a1 * a1 + a2 * a2 + a3 * a3;
  }
#pragma unroll
  for (int off = 1; off < 64; off <<= 1) ss += __shfl_xor(ss, off);
  float sd = sqrtf(ss * (1.0f / 767.0f));
  float inv = 1.0f / (sd + 1e-6f);
#pragma unroll
  for (int g = 0; g < 3; ++g) {
    float4 al = *(const float4*)&alpha[lane * 12 + g * 4];
    float4 be = *(const float4*)&beta[lane * 12 + g * 4];
    uint2 pk;
    pk.x = cvtpk(al.x * (v[g].x - mu) * inv + be.x, al.y * (v[g].y - mu) * inv + be.y);
    pk.y = cvtpk(al.z * (v[g].z - mu) * inv + be.z, al.w * (v[g].w - mu) * inv + be.w);
    *(uint2*)&orow[lane * 12 + g * 4] = pk;
  }
}

// ------- merged: wqkv fp32->bf16 + bias concat + LN1 (one launch) -----------
__global__ __launch_bounds__(256) void pre_k(const float* __restrict__ Wq,
                                             const float* __restrict__ Wk,
                                             const float* __restrict__ Wv,
                                             const float* __restrict__ bq,
                                             const float* __restrict__ bk,
                                             const float* __restrict__ bv,
                                             const float* __restrict__ x,
                                             const float* __restrict__ alpha,
                                             const float* __restrict__ beta,
                                             unsigned short* __restrict__ wqkv,
                                             float* __restrict__ bqkv,
                                             unsigned short* __restrict__ n_b) {
  const int blk = blockIdx.x;
  if (blk < 1728) {            // Wq/Wk/Wv -> wqkv rows [0,2304)
    int r = blk / 576;
    const float* src = r == 0 ? Wq : r == 1 ? Wk : Wv;
    unsigned short* dst = wqkv + (long)r * 589824;
    long off = (long)(blk - r * 576) * 1024 + threadIdx.x * 4;
    float4 v = *(const float4*)&src[off];
    uint2 pk;
    pk.x = cvtpk(v.x, v.y);
    pk.y = cvtpk(v.z, v.w);
    *(uint2*)&dst[off] = pk;
  } else if (blk == 1728) {    // bias concat
    for (int k = threadIdx.x; k < 2304; k += 256)
      bqkv[k] = k < 768 ? bq[k] : k < 1536 ? bk[k - 768] : bv[k - 1536];
  } else {                     // LN1: 4 rows per block
    int row = (blk - 1729) * 4 + (threadIdx.x >> 6);
    ln_row(x + (long)row * DD, alpha, beta, n_b + (long)row * DD, threadIdx.x & 63);
  }
}

// ---------------- LN2 standalone ----------------
__global__ __launch_bounds__(256) void layernorm_k(const float* __restrict__ x,
                                                   const float* __restrict__ alpha,
                                                   const float* __restrict__ beta,
                                                   unsigned short* __restrict__ outb) {
  int row = blockIdx.x * 4 + (threadIdx.x >> 6);
  ln_row(x + (long)row * DD, alpha, beta, outb + (long)row * DD, threadIdx.x & 63);
}

// ---------------- bf16 GEMM: C[M,N] = A[M,K] * W[N,K]^T (+bias,+res,relu) ----
// BMxBN tile, BK=64, 4 waves (2x2), global_load_lds staging.
// LDS XOR-swizzle: stage source col chunk ^= row&7 (linear LDS dest),
// fragment reads offset ^= (l15&7)<<4 -> conflict-free.
// XCD-chunked block swizzle (requires (gridDim.x*gridDim.y) % 8 == 0).
// QSC: scale cols<768 by 0.125*log2(e) (Q pre-scale for exp2-domain attn).
template <int BM, int BN, bool RELU, bool RES, bool OUTB, bool QSC>
__global__ __launch_bounds__(256, (BM == 64 || BN == 64) ? 4 : 3)
void gemm_bt(const unsigned short* __restrict__ A,
             const unsigned short* __restrict__ W,
             const float* __restrict__ bias,
             const float* __restrict__ res,
             void* __restrict__ outp,
             int M, int N, int K) {
  __shared__ __align__(16) unsigned short As[BM * 64];
  __shared__ __align__(16) unsigned short Bs[BN * 64];
  constexpr int MF = BM / 32;   // 16-wide row frags per wave
  constexpr int NF = BN / 32;   // 16-wide col frags per wave
  const int t = threadIdx.x;
  const int lane = t & 63;
  const int w = t >> 6;
  const int wr = w >> 1, wc = w & 1;
  const int l15 = lane & 15, l4 = lane >> 4;
  // XCD-chunked swizzle: contiguous chunk of blocks (sharing A-panels) per XCD
  const int nwg = gridDim.x * gridDim.y;
  const int lin = blockIdx.y * gridDim.x + blockIdx.x;
  const int u2 = (lin & 7) * (nwg >> 3) + (lin >> 3);
  const long brow = (long)(u2 / gridDim.x) * BM;
  const long bcol = (long)(u2 % gridDim.x) * BN;
  f32x4 acc[MF][NF] = {};
  const int r0 = t >> 3;                       // 0..31 (row within 32-chunk)
  const int c8s = (((t & 7) ^ (r0 & 7)) & 7) * 8;  // swizzled col (shorts)
  const int rd_swz = (l15 & 7) << 4;           // read-side XOR (bytes)

  for (int k0 = 0; k0 < K; k0 += 64) {
    __syncthreads();
#pragma unroll
    for (int p = 0; p < BM / 32; ++p)
      gload_lds16(&A[(brow + p * 32 + r0) * (long)K + k0 + c8s],
                  (char*)As + p * 4096 + w * 1024);
#pragma unroll
    for (int p = 0; p < BN / 32; ++p)
      gload_lds16(&W[(bcol + p * 32 + r0) * (long)K + k0 + c8s],
                  (char*)Bs + p * 4096 + w * 1024);
    __syncthreads();
#pragma unroll
    for (int ks = 0; ks < 2; ++ks) {
      bf16x8 a[MF], b[NF];
#pragma unroll
      for (int m = 0; m < MF; ++m)
        a[m] = *(const bf16x8*)((const char*)As +
                                (wr * (BM / 2) + m * 16 + l15) * 128 +
                                ((ks * 64 + l4 * 16) ^ rd_swz));
#pragma unroll
      for (int n = 0; n < NF; ++n)
        b[n] = *(const bf16x8*)((const char*)Bs +
                                (wc * (BN / 2) + n * 16 + l15) * 128 +
                                ((ks * 64 + l4 * 16) ^ rd_swz));
#pragma unroll
      for (int m = 0; m < MF; ++m)
#pragma unroll
        for (int n = 0; n < NF; ++n)
          acc[m][n] = __builtin_amdgcn_mfma_f32_16x16x32_bf16(a[m], b[n], acc[m][n], 0, 0, 0);
    }
  }
#pragma unroll
  for (int n = 0; n < NF; ++n) {
    const long col = bcol + wc * (BN / 2) + n * 16 + l15;
    const float bv = bias[col];
    const float sc = (QSC && col < 768) ? 0.18033688f : 1.0f;
#pragma unroll
    for (int m = 0; m < MF; ++m) {
      const long row0 = brow + wr * (BM / 2) + m * 16 + l4 * 4;
#pragma unroll
      for (int r = 0; r < 4; ++r) {
        float v = acc[m][n][r] + bv;
        if (RELU) v = fmaxf(v, 0.0f);
        if (QSC) v *= sc;
        long o = (row0 + r) * (long)N + col;
        if (RES) v += res[o];
        if (OUTB) ((unsigned short*)outp)[o] = f2b(v);
        else ((float*)outp)[o] = v;
      }
    }
  }
}

// ---------------- flash attention v14: pipelined + fused weight-cvt ---------
// Blocks [0,768): one block per (b,h,64-q-tile), 4 waves, 32 KV tiles,
// pipelined QK(i+1) || softmax+PV(i). K: 2 LDS bufs; V: 3 LDS bufs.
// tr-read V path, ones-MFMA row-sum, exp2 softmax, defer-max, cvt_pk.
// Blocks [768,996): convert Wo/W1/W2 fp32->bf16 (16384 elems/block; segment
// boundaries 589824/2162688/3735552 are multiples of 16384) -- runs in the
// idle CU slots under attention, completes before the Wo GEMM launch.
__global__ __launch_bounds__(256, 4) void attn_kernel(const unsigned short* __restrict__ qkv,
                                                      const int* __restrict__ mask,
                                                      unsigned short* __restrict__ ctx,
                                                      const float* __restrict__ Wo,
                                                      const float* __restrict__ W1,
                                                      const float* __restrict__ W2,
                                                      unsigned short* __restrict__ wo_b,
                                                      unsigned short* __restrict__ w1_b,
                                                      unsigned short* __restrict__ w2_b) {
  if (blockIdx.x >= 768) {     // fused weight conversion (block-uniform branch)
    const long base = (long)(blockIdx.x - 768) * 16384 + threadIdx.x * 4;
#pragma unroll 4
    for (int i = 0; i < 16; ++i) {
      long e = base + i * 1024;
      const float* s;
      unsigned short* d;
      long off;
      if (e < 589824) { s = Wo; d = wo_b; off = e; }
      else if (e < 2162688) { s = W1; d = w1_b; off = e - 589824; }
      else { s = W2; d = w2_b; off = e - 2162688; }
      float4 v = *(const float4*)&s[off];
      uint2 pk;
      pk.x = cvtpk(v.x, v.y);
      pk.y = cvtpk(v.z, v.w);
      *(uint2*)&d[off] = pk;
    }
    return;
  }

  __shared__ __align__(16) unsigned short Ks[2][64 * 64];  // K [key][d], XOR-swz
  __shared__ __align__(16) unsigned short Vt[3][64 * 64];  // V subtiled for tr-read
  const int t = threadIdx.x, lane = t & 63, w = t >> 6;
  const int l15 = lane & 15, l4 = lane >> 4;
  // XCD-chunked swizzle over the 768 attn blocks (768 % 8 == 0, bijective)
  const int u = (blockIdx.x & 7) * 96 + (blockIdx.x >> 3);
  const int qt = u & 31;
  const int h = (u >> 5) % 12;
  const int b = u / 384;
  const long rowB = (long)b * SS;

  // ---- mask bitmap (scratch aliased onto Vt[0]; staged only later) ----
  unsigned bm;
  {
    int* tfl = (int*)&Vt[0][0];
    const int* mb = &mask[b * SS + t * 8];
    int4 a0 = *(const int4*)mb;
    int4 a1 = *(const int4*)(mb + 4);
    int allv = (a0.x && a0.y && a0.z && a0.w && a1.x && a1.y && a1.z && a1.w) ? 1 : 0;
    allv &= __shfl_xor(allv, 1);
    allv &= __shfl_xor(allv, 2);
    allv &= __shfl_xor(allv, 4);
    if ((t & 7) == 0) tfl[t >> 3] = allv;
    __syncthreads();
    int vv = (lane < 32) ? tfl[lane] : 1;
    bm = (unsigned)__ballot(vv);   // per-wave; bit kb = tile kb fully unmasked
    __syncthreads();               // scratch dead before Vt[0] is staged
  }

  // Q fragment (B operand): lane l15 = q, elems d = ks*32 + l4*8 + j
  bf16x8 aq[2];
#pragma unroll
  for (int ks = 0; ks < 2; ++ks)
    aq[ks] = *(const bf16x8*)&qkv[(rowB + qt * 64 + w * 16 + l15) * QKV_LD +
                                  h * 64 + ks * 32 + l4 * 8];

  // K staging (gload_lds linear dest; XOR swizzle folded into global src col)
  const int krow = w * 8 + (lane >> 3);                          // +p*32
  const int kdo = (((lane & 7) ^ (lane >> 3)) & 7) << 3;         // shorts
  const unsigned short* kgbase = &qkv[(rowB + krow) * QKV_LD + 768 + h * 64 + kdo];
  const int kread_swz = (l15 & 7) << 4;

  // V staging: decode linear dest X = p*4096 + w*1024 + lane*16 into (key, d0)
  const unsigned short* vsrc[2];
#pragma unroll
  for (int p = 0; p < 2; ++p) {
    int X = p * 4096 + w * 1024 + lane * 16;
    int d_blk = X >> 11;
    int rem = X & 2047;
    int k_blk = rem >> 7;
    int krw = (rem >> 5) & 3;
    int c = (rem >> 4) & 1;
    int vkey = k_blk * 4 + krw;
    int vd0 = d_blk * 16 + c * 8;
    vsrc[p] = &qkv[(rowB + vkey) * QKV_LD + 1536 + h * 64 + vd0];
  }
  // tr-read per-lane address part; rotating V read bases (i%3: 0,1,2,...)
  const unsigned vtrl = (unsigned)(l15 * 2 + l4 * 128);
  unsigned vad0 = lds_u32(&Vt[0][0]) + vtrl;
  unsigned vad1 = lds_u32(&Vt[1][0]) + vtrl;
  unsigned vad2 = lds_u32(&Vt[2][0]) + vtrl;
  // rotating V stage-dest bases ((i+2)%3: 2,0,1,...)
  char* vdst0 = (char*)&Vt[2][0];
  char* vdst1 = (char*)&Vt[0][0];
  char* vdst2 = (char*)&Vt[1][0];
  // K read/stage bases (QK(i+1) reads parity (i+1)&1; stage(i+2) -> parity i&1)
  const char* kread = (const char*)&Ks[1][0];
  char* kdst = (char*)&Ks[0][0];

  // ones A-operand for row-sum MFMA (bf16 1.0 = 0x3F80)
  union { unsigned uu[4]; bf16x8 b8; } vone;
  vone.uu[0] = vone.uu[1] = vone.uu[2] = vone.uu[3] = 0x3F803F80u;

  f32x4 o[4] = {};
  f32x4 o4 = {};                 // row-sum accumulator (all regs = sum for q=l15)
  float mrun = -1e30f;
  f32x4 sp[4];                   // scores of tile i (being softmaxed/PV'd)

#define QK_INTO(dst, kbase)                                                     \
  { __builtin_amdgcn_s_setprio(1);                                             \
    _Pragma("unroll") for (int ks = 0; ks < 2; ++ks)                           \
    _Pragma("unroll") for (int cg = 0; cg < 4; ++cg) {                         \
      bf16x8 ak = *(const bf16x8*)((kbase) + (cg * 16 + l15) * 128 +           \
                                   ((ks * 64 + l4 * 16) ^ kread_swz));         \
      dst[cg] = __builtin_amdgcn_mfma_f32_16x16x32_bf16(ak, aq[ks], dst[cg], 0, 0, 0); \
    }                                                                           \
    __builtin_amdgcn_s_setprio(0); }

#define MASK_APPLY(dst, kb)                                                     \
  if (__builtin_expect(!((bm >> (kb)) & 1), 0)) {                              \
    const int* mb2 = &mask[b * SS + (kb) * 64 + l4 * 4];                       \
    _Pragma("unroll") for (int cg = 0; cg < 4; ++cg) {                         \
      int4 mm = *(const int4*)(mb2 + cg * 16);                                 \
      int mi[4] = {mm.x, mm.y, mm.z, mm.w};                                    \
      _Pragma("unroll") for (int r = 0; r < 4; ++r)                            \
        dst[cg][r] += mi[r] ? 0.f : -1.44269504e9f;                            \
    } }

  // ---- prologue: stage tile 0, drain, issue stage tile 1, QK(0) ----
#pragma unroll
  for (int p = 0; p < 2; ++p)
    gload_lds16(kgbase + (long)p * 32 * QKV_LD, (char*)&Ks[0][0] + p * 4096 + w * 1024);
#pragma unroll
  for (int p = 0; p < 2; ++p)
    gload_lds16(vsrc[p], (char*)&Vt[0][0] + p * 4096 + w * 1024);
  __syncthreads();
#pragma unroll
  for (int p = 0; p < 2; ++p)
    gload_lds16(kgbase + ((long)64 + p * 32) * QKV_LD, (char*)&Ks[1][0] + p * 4096 + w * 1024);
#pragma unroll
  for (int p = 0; p < 2; ++p)
    gload_lds16(vsrc[p] + (long)64 * QKV_LD, (char*)&Vt[1][0] + p * 4096 + w * 1024);
#pragma unroll
  for (int cg = 0; cg < 4; ++cg) sp[cg] = f32x4{0.f, 0.f, 0.f, 0.f};
  QK_INTO(sp, (const char*)&Ks[0][0]);
  MASK_APPLY(sp, 0);

  for (int i = 0; i < 31; ++i) {
    __syncthreads();   // stage(i+1) landed; all QK(i) reads of Ks done
    // ---- issue stage(i+2): K -> kdst (parity i&1), V -> vdst0 ((i+2)%3) ----
    if (i < 30) {
#pragma unroll
      for (int p = 0; p < 2; ++p)
        gload_lds16(kgbase + ((long)(i + 2) * 64 + p * 32) * QKV_LD,
                    kdst + p * 4096 + w * 1024);
#pragma unroll
      for (int p = 0; p < 2; ++p)
        gload_lds16(vsrc[p] + (long)(i + 2) * 64 * QKV_LD,
                    vdst0 + p * 4096 + w * 1024);
    }
    // ---- QK(i+1) from kread (MFMA pipe; overlaps softmax(i) below) ----
    f32x4 sc[4] = {};
    QK_INTO(sc, kread);
    MASK_APPLY(sc, i + 1);
    // ---- softmax(i) on sp (exp2 domain, per-q stats, q=l15) ----
    {
      float t0 = fmaxf(fmaxf(sp[0][0], sp[0][1]), sp[0][2]);
      float t1 = fmaxf(fmaxf(sp[0][3], sp[1][0]), sp[1][1]);
      float t2 = fmaxf(fmaxf(sp[1][2], sp[1][3]), sp[2][0]);
      float t3 = fmaxf(fmaxf(sp[2][1], sp[2][2]), sp[2][3]);
      float t4 = fmaxf(fmaxf(sp[3][0], sp[3][1]), sp[3][2]);
      float t5 = fmaxf(fmaxf(t0, t1), t2);
      float t6 = fmaxf(fmaxf(t3, t4), sp[3][3]);
      float pmax = fmaxf(t5, t6);
      pmax = fmaxf(pmax, __shfl_xor(pmax, 16));
      pmax = fmaxf(pmax, __shfl_xor(pmax, 32));
      if (!__all(pmax <= mrun + 8.0f)) {   // defer-max (THR=8, exp2 domain)
        float mnew = fmaxf(mrun, pmax);
        float fac = __builtin_amdgcn_exp2f(mrun - mnew);
#pragma unroll
        for (int mg = 0; mg < 4; ++mg)
#pragma unroll
          for (int r = 0; r < 4; ++r) o[mg][r] *= fac;
#pragma unroll
        for (int r = 0; r < 4; ++r) o4[r] *= fac;
        mrun = mnew;
      }
#pragma unroll
      for (int cg = 0; cg < 4; ++cg)
#pragma unroll
        for (int r = 0; r < 4; ++r)
          sp[cg][r] = __builtin_amdgcn_exp2f(sp[cg][r] - mrun);
    }
    // ---- PV(i): bp from sp, av via tr-reads of V[i%3] (vad0) ----
    __builtin_amdgcn_s_setprio(1);
#pragma unroll
    for (int ks = 0; ks < 2; ++ks) {
      union { unsigned uu[4]; bf16x8 b8; } bp;
      bp.uu[0] = cvtpk(sp[2 * ks][0], sp[2 * ks][1]);
      bp.uu[1] = cvtpk(sp[2 * ks][2], sp[2 * ks][3]);
      bp.uu[2] = cvtpk(sp[2 * ks + 1][0], sp[2 * ks + 1][1]);
      bp.uu[3] = cvtpk(sp[2 * ks + 1][2], sp[2 * ks + 1][3]);
      uint2 q0, q1, q2, q3, q4, q5, q6, q7;
      if (ks == 0) {
        asm volatile(
            "ds_read_b64_tr_b16 %0, %8 offset:0\n\t"
            "ds_read_b64_tr_b16 %1, %8 offset:512\n\t"
            "ds_read_b64_tr_b16 %2, %8 offset:2048\n\t"
            "ds_read_b64_tr_b16 %3, %8 offset:2560\n\t"
            "ds_read_b64_tr_b16 %4, %8 offset:4096\n\t"
            "ds_read_b64_tr_b16 %5, %8 offset:4608\n\t"
            "ds_read_b64_tr_b16 %6, %8 offset:6144\n\t"
            "ds_read_b64_tr_b16 %7, %8 offset:6656\n\t"
            "s_waitcnt lgkmcnt(0)"
            : "=&v"(q0), "=&v"(q1), "=&v"(q2), "=&v"(q3),
              "=&v"(q4), "=&v"(q5), "=&v"(q6), "=&v"(q7)
            : "v"(vad0));
      } else {
        asm volatile(
            "ds_read_b64_tr_b16 %0, %8 offset:1024\n\t"
            "ds_read_b64_tr_b16 %1, %8 offset:1536\n\t"
            "ds_read_b64_tr_b16 %2, %8 offset:3072\n\t"
            "ds_read_b64_tr_b16 %3, %8 offset:3584\n\t"
            "ds_read_b64_tr_b16 %4, %8 offset:5120\n\t"
            "ds_read_b64_tr_b16 %5, %8 offset:5632\n\t"
            "ds_read_b64_tr_b16 %6, %8 offset:7168\n\t"
            "ds_read_b64_tr_b16 %7, %8 offset:7680\n\t"
            "s_waitcnt lgkmcnt(0)"
            : "=&v"(q0), "=&v"(q1), "=&v"(q2), "=&v"(q3),
              "=&v"(q4), "=&v"(q5), "=&v"(q6), "=&v"(q7)
            : "v"(vad0));
      }
      union { uint2 u2[2]; bf16x8 b8; } av0, av1, av2, av3;
      av0.u2[0] = q0; av0.u2[1] = q1;
      av1.u2[0] = q2; av1.u2[1] = q3;
      av2.u2[0] = q4; av2.u2[1] = q5;
      av3.u2[0] = q6; av3.u2[1] = q7;
      o[0] = __builtin_amdgcn_mfma_f32_16x16x32_bf16(av0.b8, bp.b8, o[0], 0, 0, 0);
      o[1] = __builtin_amdgcn_mfma_f32_16x16x32_bf16(av1.b8, bp.b8, o[1], 0, 0, 0);
      o[2] = __builtin_amdgcn_mfma_f32_16x16x32_bf16(av2.b8, bp.b8, o[2], 0, 0, 0);
      o[3] = __builtin_amdgcn_mfma_f32_16x16x32_bf16(av3.b8, bp.b8, o[3], 0, 0, 0);
      o4 = __builtin_amdgcn_mfma_f32_16x16x32_bf16(vone.b8, bp.b8, o4, 0, 0, 0);
    }
    __builtin_amdgcn_s_setprio(0);
    // ---- rotate: sp <- sc; swap K bases; rotate V bases ----
#pragma unroll
    for (int cg = 0; cg < 4; ++cg) sp[cg] = sc[cg];
    { const char* tk = kread; kread = kdst; kdst = (char*)tk; }
    { unsigned tv = vad0; vad0 = vad1; vad1 = vad2; vad2 = tv; }
    { char* td = vdst0; vdst0 = vdst1; vdst1 = vdst2; vdst2 = td; }
  }

  // ---- epilogue tile 31: softmax(31) on sp + PV(31) from vad0 (Vt[1]) ----
  {
    float t0 = fmaxf(fmaxf(sp[0][0], sp[0][1]), sp[0][2]);
    float t1 = fmaxf(fmaxf(sp[0][3], sp[1][0]), sp[1][1]);
    float t2 = fmaxf(fmaxf(sp[1][2], sp[1][3]), sp[2][0]);
    float t3 = fmaxf(fmaxf(sp[2][1], sp[2][2]), sp[2][3]);
    float t4 = fmaxf(fmaxf(sp[3][0], sp[3][1]), sp[3][2]);
    float t5 = fmaxf(fmaxf(t0, t1), t2);
    float t6 = fmaxf(fmaxf(t3, t4), sp[3][3]);
    float pmax = fmaxf(t5, t6);
    pmax = fmaxf(pmax, __shfl_xor(pmax, 16));
    pmax = fmaxf(pmax, __shfl_xor(pmax, 32));
    if (!__all(pmax <= mrun + 8.0f)) {
      float mnew = fmaxf(mrun, pmax);
      float fac = __builtin_amdgcn_exp2f(mrun - mnew);
#pragma unroll
      for (int mg = 0; mg < 4; ++mg)
#pragma unroll
        for (int r = 0; r < 4; ++r) o[mg][r] *= fac;
#pragma unroll
      for (int r = 0; r < 4; ++r) o4[r] *= fac;
      mrun = mnew;
    }
#pragma unroll
    for (int cg = 0; cg < 4; ++cg)
#pragma unroll
      for (int r = 0; r < 4; ++r)
        sp[cg][r] = __builtin_amdgcn_exp2f(sp[cg][r] - mrun);
#pragma unroll
    for (int ks = 0; ks < 2; ++ks) {
      union { unsigned uu[4]; bf16x8 b8; } bp;
      bp.uu[0] = cvtpk(sp[2 * ks][0], sp[2 * ks][1]);
      bp.uu[1] = cvtpk(sp[2 * ks][2], sp[2 * ks][3]);
      bp.uu[2] = cvtpk(sp[2 * ks + 1][0], sp[2 * ks + 1][1]);
      bp.uu[3] = cvtpk(sp[2 * ks + 1][2], sp[2 * ks + 1][3]);
      uint2 q0, q1, q2, q3, q4, q5, q6, q7;
      if (ks == 0) {
        asm volatile(
            "ds_read_b64_tr_b16 %0, %8 offset:0\n\t"
            "ds_read_b64_tr_b16 %1, %8 offset:512\n\t"
            "ds_read_b64_tr_b16 %2, %8 offset:2048\n\t"
            "ds_read_b64_tr_b16 %3, %8 offset:2560\n\t"
            "ds_read_b64_tr_b16 %4, %8 offset:4096\n\t"
            "ds_read_b64_tr_b16 %5, %8 offset:4608\n\t"
            "ds_read_b64_tr_b16 %6, %8 offset:6144\n\t"
            "ds_read_b64_tr_b16 %7, %8 offset:6656\n\t"
            "s_waitcnt lgkmcnt(0)"
            : "=&v"(q0), "=&v"(q1), "=&v"(q2), "=&v"(q3),
              "=&v"(q4), "=&v"(q5), "=&v"(q6), "=&v"(q7)
            : "v"(vad0));
      } else {
        asm volatile(
            "ds_read_b64_tr_b16 %0, %8 offset:1024\n\t"
            "ds_read_b64_tr_b16 %1, %8 offset:1536\n\t"
            "ds_read_b64_tr_b16 %2, %8 offset:3072\n\t"
            "ds_read_b64_tr_b16 %3, %8 offset:3584\n\t"
            "ds_read_b64_tr_b16 %4, %8 offset:5120\n\t"
            "ds_read_b64_tr_b16 %5, %8 offset:5632\n\t"
            "ds_read_b64_tr_b16 %6, %8 offset:7168\n\t"
            "ds_read_b64_tr_b16 %7, %8 offset:7680\n\t"
            "s_waitcnt lgkmcnt(0)"
            : "=&v"(q0), "=&v"(q1), "=&v"(q2), "=&v"(q3),
              "=&v"(q4), "=&v"(q5), "=&v"(q6), "=&v"(q7)
            : "v"(vad0));
      }
      union { uint2 u2[2]; bf16x8 b8; } av0, av1, av2, av3;
      av0.u2[0] = q0; av0.u2[1] = q1;
      av1.u2[0] = q2; av1.u2[1] = q3;
      av2.u2[0] = q4; av2.u2[1] = q5;
      av3.u2[0] = q6; av3.u2[1] = q7;
      o[0] = __builtin_amdgcn_mfma_f32_16x16x32_bf16(av0.b8, bp.b8, o[0], 0, 0, 0);
      o[1] = __builtin_amdgcn_mfma_f32_16x16x32_bf16(av1.b8, bp.b8, o[1], 0, 0, 0);
      o[2] = __builtin_amdgcn_mfma_f32_16x16x32_bf16(av2.b8, bp.b8, o[2], 0, 0, 0);
      o[3] = __builtin_amdgcn_mfma_f32_16x16x32_bf16(av3.b8, bp.b8, o[3], 0, 0, 0);
      o4 = __builtin_amdgcn_mfma_f32_16x16x32_bf16(vone.b8, bp.b8, o4, 0, 0, 0);
    }
  }
#undef QK_INTO
#undef MASK_APPLY

  // ---- epilogue: O^T regs hold col q=l15, row d=mg*16+l4*4+r; o4 = lsum ----
  const float inv = 1.0f / o4[0];
  const long obase = (rowB + qt * 64 + w * 16 + l15) * DD + h * 64 + l4 * 4;
#pragma unroll
  for (int mg = 0; mg < 4; ++mg) {
    *(unsigned*)&ctx[obase + mg * 16] = cvtpk(o[mg][0] * inv, o[mg][1] * inv);
    *(unsigned*)&ctx[obase + mg * 16 + 2] = cvtpk(o[mg][2] * inv, o[mg][3] * inv);
  }
}

// ---------------- workspace layout (bytes) ----------------
static const size_t OFF_WQKV = 0;          // 2304*768*2  = 3538944
static const size_t OFF_WO = 3538944;      // 768*768*2   = 1179648
static const size_t OFF_W1 = 4718592;      // 2048*768*2  = 3145728
static const size_t OFF_W2 = 7864320;      // 768*2048*2  = 3145728
static const size_t OFF_BQKV = 11010048;   // 2304*4
static const size_t OFF_N = 11019264;      // 4096*768*2  (reused for n2)
static const size_t OFF_QKV = 17310720;    // 4096*2304*2 (reused for h)
static const size_t OFF_CTX = 36185088;    // 4096*768*2
static const size_t OFF_X1 = 42476544;     // 4096*768*4
// total = 55059456 bytes

extern "C" void kernel_launch(void* const* d_in, const int* in_sizes, int n_in,
                              void* d_out, int out_size, void* d_ws, size_t ws_size,
                              hipStream_t stream) {
  (void)in_sizes; (void)n_in; (void)out_size; (void)ws_size;
  const float* x = (const float*)d_in[0];
  const int* mask = (const int*)d_in[1];
  const float* Wq = (const float*)d_in[2];
  const float* bq = (const float*)d_in[3];
  const float* Wk = (const float*)d_in[4];
  const float* bk = (const float*)d_in[5];
  const float* Wv = (const float*)d_in[6];
  const float* bv = (const float*)d_in[7];
  const float* Wo = (const float*)d_in[8];
  const float* bo = (const float*)d_in[9];
  const float* W1 = (const float*)d_in[10];
  const float* b1 = (const float*)d_in[11];
  const float* W2 = (const float*)d_in[12];
  const float* b2 = (const float*)d_in[13];
  const float* alpha = (const float*)d_in[14];
  const float* beta = (const float*)d_in[15];

  char* ws = (char*)d_ws;
  unsigned short* wqkv = (unsigned short*)(ws + OFF_WQKV);
  unsigned short* wo_b = (unsigned short*)(ws + OFF_WO);
  unsigned short* w1_b = (unsigned short*)(ws + OFF_W1);
  unsigned short* w2_b = (unsigned short*)(ws + OFF_W2);
  float* bqkv = (float*)(ws + OFF_BQKV);
  unsigned short* n_b = (unsigned short*)(ws + OFF_N);
  unsigned short* qkv_b = (unsigned short*)(ws + OFF_QKV);
  unsigned short* h_b = qkv_b;  // reuse after attention
  unsigned short* ctx_b = (unsigned short*)(ws + OFF_CTX);
  float* x1_f = (float*)(ws + OFF_X1);
  float* out_f = (float*)d_out;

  // wqkv->bf16 + bias concat + LN1 (1728 cvt + 1 bias + 1024 LN blocks)
  pre_k<<<2753, 256, 0, stream>>>(Wq, Wk, Wv, bq, bk, bv,
                                  x, alpha, beta, wqkv, bqkv, n_b);
  // fused QKV GEMM: [4096,768] x [2304,768]^T -> [4096,2304] bf16, Q pre-scaled
  gemm_bt<128, 128, false, false, true, true><<<dim3(18, 32), 256, 0, stream>>>(
      n_b, wqkv, bqkv, nullptr, qkv_b, BSR, QKV_LD, DD);
  // attention (768 blocks) + fused Wo/W1/W2 conversion (228 blocks)
  attn_kernel<<<996, 256, 0, stream>>>(qkv_b, mask, ctx_b,
                                       Wo, W1, W2, wo_b, w1_b, w2_b);
  // Wo GEMM + residual(x) -> x1 fp32 (64x64 tiles: 768 blocks, 3/CU)
  gemm_bt<64, 64, false, true, false, false><<<dim3(12, 64), 256, 0, stream>>>(
      ctx_b, wo_b, bo, x, x1_f, BSR, DD, DD);
  // LN2
  layernorm_k<<<1024, 256, 0, stream>>>(x1_f, alpha, beta, n_b);
  // FFN1 + relu -> h bf16 (64x128 tiles: 1024 blocks, exactly 4/CU)
  gemm_bt<64, 128, true, false, true, false><<<dim3(16, 64), 256, 0, stream>>>(
      n_b, w1_b, b1, nullptr, h_b, BSR, DFFF, DD);
  // FFN2 + residual(x1) -> out fp32 (64x64 tiles: 768 blocks, 3/CU)
  gemm_bt<64, 64, false, true, false, false><<<dim3(12, 64), 256, 0, stream>>>(
      h_b, w2_b, b2, x1_f, out_f, BSR, DD, DFFF);
}

// Round 21
// 131.695 us; speedup vs baseline: 1.0278x; 1.0090x over previous
//
#include <hip/hip_runtime.h>

// EncoderLayer: pre-norm MHA + FFN, B=2 S=2048 D=768 H=12 DFF=2048, fp32 I/O,
// bf16 MFMA internals. Pipeline:
//   pre (wqkv->bf16 + bias concat + LN1), QKV-GEMM(fused, Q pre-scaled, 128x96),
//   flash-attn (pipelined; + 228 fused blocks converting Wo/W1/W2 under attn),
//   Wo-GEMM+res (64x64), LN2, FFN1+relu (64x128), FFN2+res (64x64) -> d_out
// GEMM LDS tiles XOR-swizzled: 0 bank conflicts on ds_read_b128.
#define SS   2048
#define DD   768
#define HH   12
#define DFFF 2048
#define BSR  4096      // B*S
#define QKV_LD 2304

typedef __attribute__((ext_vector_type(8))) short bf16x8;
typedef __attribute__((ext_vector_type(4))) float f32x4;

__device__ __forceinline__ unsigned short f2b(float f) {
  union { float f; unsigned u; } x; x.f = f;
  unsigned r = (x.u + 0x7FFFu + ((x.u >> 16) & 1u)) >> 16;
  return (unsigned short)r;
}

__device__ __forceinline__ unsigned cvtpk(float lo, float hi) {
  unsigned r;
  asm("v_cvt_pk_bf16_f32 %0, %1, %2" : "=v"(r) : "v"(lo), "v"(hi));
  return r;
}

__device__ __forceinline__ void gload_lds16(const void* g, void* l) {
  __builtin_amdgcn_global_load_lds(
      (const __attribute__((address_space(1))) unsigned int*)g,
      (__attribute__((address_space(3))) unsigned int*)l,
      16, 0, 0);
}

// low 32 bits of a flat __shared__ pointer = LDS byte offset on gfx9
__device__ __forceinline__ unsigned lds_u32(const void* p) {
  return (unsigned)(unsigned long long)p;
}

// ---------------- LayerNorm row (torch semantics: ddof=1, eps on std) -------
__device__ __forceinline__ void ln_row(const float* __restrict__ xr,
                                       const float* __restrict__ alpha,
                                       const float* __restrict__ beta,
                                       unsigned short* __restrict__ orow, int lane) {
  float4 v[3];
#pragma unroll
  for (int g = 0; g < 3; ++g) v[g] = *(const float4*)&xr[lane * 12 + g * 4];
  float sum = 0.f;
#pragma unroll
  for (int g = 0; g < 3; ++g) sum += v[g].x + v[g].y + v[g].z + v[g].w;
#pragma unroll
  for (int off = 1; off < 64; off <<= 1) sum += __shfl_xor(sum, off);
  float mu = sum * (1.0f / 768.0f);
  float ss = 0.f;
#pragma unroll
  for (int g = 0; g < 3; ++g) {
    float a0 = v[g].x - mu, a1 = v[g].y - mu, a2 = v[g].z - mu, a3 = v[g].w - mu;
    ss += a0 * a0 + a1 * a1 + a2 * a2 + a3 * a3;
  }
#pragma unroll
  for (int off = 1; off < 64; off <<= 1) ss += __shfl_xor(ss, off);
  float sd = sqrtf(ss * (1.0f / 767.0f));
  float inv = 1.0f / (sd + 1e-6f);
#pragma unroll
  for (int g = 0; g < 3; ++g) {
    float4 al = *(const float4*)&alpha[lane * 12 + g * 4];
    float4 be = *(const float4*)&beta[lane * 12 + g * 4];
    uint2 pk;
    pk.x = cvtpk(al.x * (v[g].x - mu) * inv + be.x, al.y * (v[g].y - mu) * inv + be.y);
    pk.y = cvtpk(al.z * (v[g].z - mu) * inv + be.z, al.w * (v[g].w - mu) * inv + be.w);
    *(uint2*)&orow[lane * 12 + g * 4] = pk;
  }
}

// ------- merged: wqkv fp32->bf16 + bias concat + LN1 (one launch) -----------
__global__ __launch_bounds__(256) void pre_k(const float* __restrict__ Wq,
                                             const float* __restrict__ Wk,
                                             const float* __restrict__ Wv,
                                             const float* __restrict__ bq,
                                             const float* __restrict__ bk,
                                             const float* __restrict__ bv,
                                             const float* __restrict__ x,
                                             const float* __restrict__ alpha,
                                             const float* __restrict__ beta,
                                             unsigned short* __restrict__ wqkv,
                                             float* __restrict__ bqkv,
                                             unsigned short* __restrict__ n_b) {
  const int blk = blockIdx.x;
  if (blk < 1728) {            // Wq/Wk/Wv -> wqkv rows [0,2304)
    int r = blk / 576;
    const float* src = r == 0 ? Wq : r == 1 ? Wk : Wv;
    unsigned short* dst = wqkv + (long)r * 589824;
    long off = (long)(blk - r * 576) * 1024 + threadIdx.x * 4;
    float4 v = *(const float4*)&src[off];
    uint2 pk;
    pk.x = cvtpk(v.x, v.y);
    pk.y = cvtpk(v.z, v.w);
    *(uint2*)&dst[off] = pk;
  } else if (blk == 1728) {    // bias concat
    for (int k = threadIdx.x; k < 2304; k += 256)
      bqkv[k] = k < 768 ? bq[k] : k < 1536 ? bk[k - 768] : bv[k - 1536];
  } else {                     // LN1: 4 rows per block
    int row = (blk - 1729) * 4 + (threadIdx.x >> 6);
    ln_row(x + (long)row * DD, alpha, beta, n_b + (long)row * DD, threadIdx.x & 63);
  }
}

// ---------------- LN2 standalone ----------------
__global__ __launch_bounds__(256) void layernorm_k(const float* __restrict__ x,
                                                   const float* __restrict__ alpha,
                                                   const float* __restrict__ beta,
                                                   unsigned short* __restrict__ outb) {
  int row = blockIdx.x * 4 + (threadIdx.x >> 6);
  ln_row(x + (long)row * DD, alpha, beta, outb + (long)row * DD, threadIdx.x & 63);
}

// ---------------- bf16 GEMM: C[M,N] = A[M,K] * W[N,K]^T (+bias,+res,relu) ----
// BMxBN tile, BK=64, 4 waves (2x2), global_load_lds staging.
// LDS XOR-swizzle: stage source col chunk ^= row&7 (linear LDS dest),
// fragment reads offset ^= (l15&7)<<4 -> conflict-free.
// XCD-chunked block swizzle (requires (gridDim.x*gridDim.y) % 8 == 0).
// QSC: scale cols<768 by 0.125*log2(e) (Q pre-scale for exp2-domain attn).
template <int BM, int BN, bool RELU, bool RES, bool OUTB, bool QSC>
__global__ __launch_bounds__(256, (BM == 64 || BN == 64) ? 4 : 3)
void gemm_bt(const unsigned short* __restrict__ A,
             const unsigned short* __restrict__ W,
             const float* __restrict__ bias,
             const float* __restrict__ res,
             void* __restrict__ outp,
             int M, int N, int K) {
  __shared__ __align__(16) unsigned short As[BM * 64];
  __shared__ __align__(16) unsigned short Bs[BN * 64];
  constexpr int MF = BM / 32;   // 16-wide row frags per wave
  constexpr int NF = BN / 32;   // 16-wide col frags per wave
  const int t = threadIdx.x;
  const int lane = t & 63;
  const int w = t >> 6;
  const int wr = w >> 1, wc = w & 1;
  const int l15 = lane & 15, l4 = lane >> 4;
  // XCD-chunked swizzle: contiguous chunk of blocks (sharing A-panels) per XCD
  const int nwg = gridDim.x * gridDim.y;
  const int lin = blockIdx.y * gridDim.x + blockIdx.x;
  const int u2 = (lin & 7) * (nwg >> 3) + (lin >> 3);
  const long brow = (long)(u2 / gridDim.x) * BM;
  const long bcol = (long)(u2 % gridDim.x) * BN;
  f32x4 acc[MF][NF] = {};
  const int r0 = t >> 3;                       // 0..31 (row within 32-chunk)
  const int c8s = (((t & 7) ^ (r0 & 7)) & 7) * 8;  // swizzled col (shorts)
  const int rd_swz = (l15 & 7) << 4;           // read-side XOR (bytes)

  for (int k0 = 0; k0 < K; k0 += 64) {
    __syncthreads();
#pragma unroll
    for (int p = 0; p < BM / 32; ++p)
      gload_lds16(&A[(brow + p * 32 + r0) * (long)K + k0 + c8s],
                  (char*)As + p * 4096 + w * 1024);
#pragma unroll
    for (int p = 0; p < BN / 32; ++p)
      gload_lds16(&W[(bcol + p * 32 + r0) * (long)K + k0 + c8s],
                  (char*)Bs + p * 4096 + w * 1024);
    __syncthreads();
#pragma unroll
    for (int ks = 0; ks < 2; ++ks) {
      bf16x8 a[MF], b[NF];
#pragma unroll
      for (int m = 0; m < MF; ++m)
        a[m] = *(const bf16x8*)((const char*)As +
                                (wr * (BM / 2) + m * 16 + l15) * 128 +
                                ((ks * 64 + l4 * 16) ^ rd_swz));
#pragma unroll
      for (int n = 0; n < NF; ++n)
        b[n] = *(const bf16x8*)((const char*)Bs +
                                (wc * (BN / 2) + n * 16 + l15) * 128 +
                                ((ks * 64 + l4 * 16) ^ rd_swz));
#pragma unroll
      for (int m = 0; m < MF; ++m)
#pragma unroll
        for (int n = 0; n < NF; ++n)
          acc[m][n] = __builtin_amdgcn_mfma_f32_16x16x32_bf16(a[m], b[n], acc[m][n], 0, 0, 0);
    }
  }
#pragma unroll
  for (int n = 0; n < NF; ++n) {
    const long col = bcol + wc * (BN / 2) + n * 16 + l15;
    const float bv = bias[col];
    const float sc = (QSC && col < 768) ? 0.18033688f : 1.0f;
#pragma unroll
    for (int m = 0; m < MF; ++m) {
      const long row0 = brow + wr * (BM / 2) + m * 16 + l4 * 4;
#pragma unroll
      for (int r = 0; r < 4; ++r) {
        float v = acc[m][n][r] + bv;
        if (RELU) v = fmaxf(v, 0.0f);
        if (QSC) v *= sc;
        long o = (row0 + r) * (long)N + col;
        if (RES) v += res[o];
        if (OUTB) ((unsigned short*)outp)[o] = f2b(v);
        else ((float*)outp)[o] = v;
      }
    }
  }
}

// ---------------- flash attention v14: pipelined + fused weight-cvt ---------
// Blocks [0,768): one block per (b,h,64-q-tile), 4 waves, 32 KV tiles,
// pipelined QK(i+1) || softmax+PV(i). K: 2 LDS bufs; V: 3 LDS bufs.
// tr-read V path, ones-MFMA row-sum, exp2 softmax, defer-max, cvt_pk.
// Blocks [768,996): convert Wo/W1/W2 fp32->bf16 under attention.
__global__ __launch_bounds__(256, 4) void attn_kernel(const unsigned short* __restrict__ qkv,
                                                      const int* __restrict__ mask,
                                                      unsigned short* __restrict__ ctx,
                                                      const float* __restrict__ Wo,
                                                      const float* __restrict__ W1,
                                                      const float* __restrict__ W2,
                                                      unsigned short* __restrict__ wo_b,
                                                      unsigned short* __restrict__ w1_b,
                                                      unsigned short* __restrict__ w2_b) {
  if (blockIdx.x >= 768) {     // fused weight conversion (block-uniform branch)
    const long base = (long)(blockIdx.x - 768) * 16384 + threadIdx.x * 4;
#pragma unroll 4
    for (int i = 0; i < 16; ++i) {
      long e = base + i * 1024;
      const float* s;
      unsigned short* d;
      long off;
      if (e < 589824) { s = Wo; d = wo_b; off = e; }
      else if (e < 2162688) { s = W1; d = w1_b; off = e - 589824; }
      else { s = W2; d = w2_b; off = e - 2162688; }
      float4 v = *(const float4*)&s[off];
      uint2 pk;
      pk.x = cvtpk(v.x, v.y);
      pk.y = cvtpk(v.z, v.w);
      *(uint2*)&d[off] = pk;
    }
    return;
  }

  __shared__ __align__(16) unsigned short Ks[2][64 * 64];  // K [key][d], XOR-swz
  __shared__ __align__(16) unsigned short Vt[3][64 * 64];  // V subtiled for tr-read
  const int t = threadIdx.x, lane = t & 63, w = t >> 6;
  const int l15 = lane & 15, l4 = lane >> 4;
  // XCD-chunked swizzle over the 768 attn blocks (768 % 8 == 0, bijective)
  const int u = (blockIdx.x & 7) * 96 + (blockIdx.x >> 3);
  const int qt = u & 31;
  const int h = (u >> 5) % 12;
  const int b = u / 384;
  const long rowB = (long)b * SS;

  // ---- mask bitmap (scratch aliased onto Vt[0]; staged only later) ----
  unsigned bm;
  {
    int* tfl = (int*)&Vt[0][0];
    const int* mb = &mask[b * SS + t * 8];
    int4 a0 = *(const int4*)mb;
    int4 a1 = *(const int4*)(mb + 4);
    int allv = (a0.x && a0.y && a0.z && a0.w && a1.x && a1.y && a1.z && a1.w) ? 1 : 0;
    allv &= __shfl_xor(allv, 1);
    allv &= __shfl_xor(allv, 2);
    allv &= __shfl_xor(allv, 4);
    if ((t & 7) == 0) tfl[t >> 3] = allv;
    __syncthreads();
    int vv = (lane < 32) ? tfl[lane] : 1;
    bm = (unsigned)__ballot(vv);   // per-wave; bit kb = tile kb fully unmasked
    __syncthreads();               // scratch dead before Vt[0] is staged
  }

  // Q fragment (B operand): lane l15 = q, elems d = ks*32 + l4*8 + j
  bf16x8 aq[2];
#pragma unroll
  for (int ks = 0; ks < 2; ++ks)
    aq[ks] = *(const bf16x8*)&qkv[(rowB + qt * 64 + w * 16 + l15) * QKV_LD +
                                  h * 64 + ks * 32 + l4 * 8];

  // K staging (gload_lds linear dest; XOR swizzle folded into global src col)
  const int krow = w * 8 + (lane >> 3);                          // +p*32
  const int kdo = (((lane & 7) ^ (lane >> 3)) & 7) << 3;         // shorts
  const unsigned short* kgbase = &qkv[(rowB + krow) * QKV_LD + 768 + h * 64 + kdo];
  const int kread_swz = (l15 & 7) << 4;

  // V staging: decode linear dest X = p*4096 + w*1024 + lane*16 into (key, d0)
  const unsigned short* vsrc[2];
#pragma unroll
  for (int p = 0; p < 2; ++p) {
    int X = p * 4096 + w * 1024 + lane * 16;
    int d_blk = X >> 11;
    int rem = X & 2047;
    int k_blk = rem >> 7;
    int krw = (rem >> 5) & 3;
    int c = (rem >> 4) & 1;
    int vkey = k_blk * 4 + krw;
    int vd0 = d_blk * 16 + c * 8;
    vsrc[p] = &qkv[(rowB + vkey) * QKV_LD + 1536 + h * 64 + vd0];
  }
  // tr-read per-lane address part; rotating V read bases (i%3: 0,1,2,...)
  const unsigned vtrl = (unsigned)(l15 * 2 + l4 * 128);
  unsigned vad0 = lds_u32(&Vt[0][0]) + vtrl;
  unsigned vad1 = lds_u32(&Vt[1][0]) + vtrl;
  unsigned vad2 = lds_u32(&Vt[2][0]) + vtrl;
  // rotating V stage-dest bases ((i+2)%3: 2,0,1,...)
  char* vdst0 = (char*)&Vt[2][0];
  char* vdst1 = (char*)&Vt[0][0];
  char* vdst2 = (char*)&Vt[1][0];
  // K read/stage bases (QK(i+1) reads parity (i+1)&1; stage(i+2) -> parity i&1)
  const char* kread = (const char*)&Ks[1][0];
  char* kdst = (char*)&Ks[0][0];

  // ones A-operand for row-sum MFMA (bf16 1.0 = 0x3F80)
  union { unsigned uu[4]; bf16x8 b8; } vone;
  vone.uu[0] = vone.uu[1] = vone.uu[2] = vone.uu[3] = 0x3F803F80u;

  f32x4 o[4] = {};
  f32x4 o4 = {};                 // row-sum accumulator (all regs = sum for q=l15)
  float mrun = -1e30f;
  f32x4 sp[4];                   // scores of tile i (being softmaxed/PV'd)

#define QK_INTO(dst, kbase)                                                     \
  { __builtin_amdgcn_s_setprio(1);                                             \
    _Pragma("unroll") for (int ks = 0; ks < 2; ++ks)                           \
    _Pragma("unroll") for (int cg = 0; cg < 4; ++cg) {                         \
      bf16x8 ak = *(const bf16x8*)((kbase) + (cg * 16 + l15) * 128 +           \
                                   ((ks * 64 + l4 * 16) ^ kread_swz));         \
      dst[cg] = __builtin_amdgcn_mfma_f32_16x16x32_bf16(ak, aq[ks], dst[cg], 0, 0, 0); \
    }                                                                           \
    __builtin_amdgcn_s_setprio(0); }

#define MASK_APPLY(dst, kb)                                                     \
  if (__builtin_expect(!((bm >> (kb)) & 1), 0)) {                              \
    const int* mb2 = &mask[b * SS + (kb) * 64 + l4 * 4];                       \
    _Pragma("unroll") for (int cg = 0; cg < 4; ++cg) {                         \
      int4 mm = *(const int4*)(mb2 + cg * 16);                                 \
      int mi[4] = {mm.x, mm.y, mm.z, mm.w};                                    \
      _Pragma("unroll") for (int r = 0; r < 4; ++r)                            \
        dst[cg][r] += mi[r] ? 0.f : -1.44269504e9f;                            \
    } }

  // ---- prologue: stage tile 0, drain, issue stage tile 1, QK(0) ----
#pragma unroll
  for (int p = 0; p < 2; ++p)
    gload_lds16(kgbase + (long)p * 32 * QKV_LD, (char*)&Ks[0][0] + p * 4096 + w * 1024);
#pragma unroll
  for (int p = 0; p < 2; ++p)
    gload_lds16(vsrc[p], (char*)&Vt[0][0] + p * 4096 + w * 1024);
  __syncthreads();
#pragma unroll
  for (int p = 0; p < 2; ++p)
    gload_lds16(kgbase + ((long)64 + p * 32) * QKV_LD, (char*)&Ks[1][0] + p * 4096 + w * 1024);
#pragma unroll
  for (int p = 0; p < 2; ++p)
    gload_lds16(vsrc[p] + (long)64 * QKV_LD, (char*)&Vt[1][0] + p * 4096 + w * 1024);
#pragma unroll
  for (int cg = 0; cg < 4; ++cg) sp[cg] = f32x4{0.f, 0.f, 0.f, 0.f};
  QK_INTO(sp, (const char*)&Ks[0][0]);
  MASK_APPLY(sp, 0);

  for (int i = 0; i < 31; ++i) {
    __syncthreads();   // stage(i+1) landed; all QK(i) reads of Ks done
    // ---- issue stage(i+2): K -> kdst (parity i&1), V -> vdst0 ((i+2)%3) ----
    if (i < 30) {
#pragma unroll
      for (int p = 0; p < 2; ++p)
        gload_lds16(kgbase + ((long)(i + 2) * 64 + p * 32) * QKV_LD,
                    kdst + p * 4096 + w * 1024);
#pragma unroll
      for (int p = 0; p < 2; ++p)
        gload_lds16(vsrc[p] + (long)(i + 2) * 64 * QKV_LD,
                    vdst0 + p * 4096 + w * 1024);
    }
    // ---- QK(i+1) from kread (MFMA pipe; overlaps softmax(i) below) ----
    f32x4 sc[4] = {};
    QK_INTO(sc, kread);
    MASK_APPLY(sc, i + 1);
    // ---- softmax(i) on sp (exp2 domain, per-q stats, q=l15) ----
    {
      float t0 = fmaxf(fmaxf(sp[0][0], sp[0][1]), sp[0][2]);
      float t1 = fmaxf(fmaxf(sp[0][3], sp[1][0]), sp[1][1]);
      float t2 = fmaxf(fmaxf(sp[1][2], sp[1][3]), sp[2][0]);
      float t3 = fmaxf(fmaxf(sp[2][1], sp[2][2]), sp[2][3]);
      float t4 = fmaxf(fmaxf(sp[3][0], sp[3][1]), sp[3][2]);
      float t5 = fmaxf(fmaxf(t0, t1), t2);
      float t6 = fmaxf(fmaxf(t3, t4), sp[3][3]);
      float pmax = fmaxf(t5, t6);
      pmax = fmaxf(pmax, __shfl_xor(pmax, 16));
      pmax = fmaxf(pmax, __shfl_xor(pmax, 32));
      if (!__all(pmax <= mrun + 8.0f)) {   // defer-max (THR=8, exp2 domain)
        float mnew = fmaxf(mrun, pmax);
        float fac = __builtin_amdgcn_exp2f(mrun - mnew);
#pragma unroll
        for (int mg = 0; mg < 4; ++mg)
#pragma unroll
          for (int r = 0; r < 4; ++r) o[mg][r] *= fac;
#pragma unroll
        for (int r = 0; r < 4; ++r) o4[r] *= fac;
        mrun = mnew;
      }
#pragma unroll
      for (int cg = 0; cg < 4; ++cg)
#pragma unroll
        for (int r = 0; r < 4; ++r)
          sp[cg][r] = __builtin_amdgcn_exp2f(sp[cg][r] - mrun);
    }
    // ---- PV(i): bp from sp, av via tr-reads of V[i%3] (vad0) ----
    __builtin_amdgcn_s_setprio(1);
#pragma unroll
    for (int ks = 0; ks < 2; ++ks) {
      union { unsigned uu[4]; bf16x8 b8; } bp;
      bp.uu[0] = cvtpk(sp[2 * ks][0], sp[2 * ks][1]);
      bp.uu[1] = cvtpk(sp[2 * ks][2], sp[2 * ks][3]);
      bp.uu[2] = cvtpk(sp[2 * ks + 1][0], sp[2 * ks + 1][1]);
      bp.uu[3] = cvtpk(sp[2 * ks + 1][2], sp[2 * ks + 1][3]);
      uint2 q0, q1, q2, q3, q4, q5, q6, q7;
      if (ks == 0) {
        asm volatile(
            "ds_read_b64_tr_b16 %0, %8 offset:0\n\t"
            "ds_read_b64_tr_b16 %1, %8 offset:512\n\t"
            "ds_read_b64_tr_b16 %2, %8 offset:2048\n\t"
            "ds_read_b64_tr_b16 %3, %8 offset:2560\n\t"
            "ds_read_b64_tr_b16 %4, %8 offset:4096\n\t"
            "ds_read_b64_tr_b16 %5, %8 offset:4608\n\t"
            "ds_read_b64_tr_b16 %6, %8 offset:6144\n\t"
            "ds_read_b64_tr_b16 %7, %8 offset:6656\n\t"
            "s_waitcnt lgkmcnt(0)"
            : "=&v"(q0), "=&v"(q1), "=&v"(q2), "=&v"(q3),
              "=&v"(q4), "=&v"(q5), "=&v"(q6), "=&v"(q7)
            : "v"(vad0));
      } else {
        asm volatile(
            "ds_read_b64_tr_b16 %0, %8 offset:1024\n\t"
            "ds_read_b64_tr_b16 %1, %8 offset:1536\n\t"
            "ds_read_b64_tr_b16 %2, %8 offset:3072\n\t"
            "ds_read_b64_tr_b16 %3, %8 offset:3584\n\t"
            "ds_read_b64_tr_b16 %4, %8 offset:5120\n\t"
            "ds_read_b64_tr_b16 %5, %8 offset:5632\n\t"
            "ds_read_b64_tr_b16 %6, %8 offset:7168\n\t"
            "ds_read_b64_tr_b16 %7, %8 offset:7680\n\t"
            "s_waitcnt lgkmcnt(0)"
            : "=&v"(q0), "=&v"(q1), "=&v"(q2), "=&v"(q3),
              "=&v"(q4), "=&v"(q5), "=&v"(q6), "=&v"(q7)
            : "v"(vad0));
      }
      union { uint2 u2[2]; bf16x8 b8; } av0, av1, av2, av3;
      av0.u2[0] = q0; av0.u2[1] = q1;
      av1.u2[0] = q2; av1.u2[1] = q3;
      av2.u2[0] = q4; av2.u2[1] = q5;
      av3.u2[0] = q6; av3.u2[1] = q7;
      o[0] = __builtin_amdgcn_mfma_f32_16x16x32_bf16(av0.b8, bp.b8, o[0], 0, 0, 0);
      o[1] = __builtin_amdgcn_mfma_f32_16x16x32_bf16(av1.b8, bp.b8, o[1], 0, 0, 0);
      o[2] = __builtin_amdgcn_mfma_f32_16x16x32_bf16(av2.b8, bp.b8, o[2], 0, 0, 0);
      o[3] = __builtin_amdgcn_mfma_f32_16x16x32_bf16(av3.b8, bp.b8, o[3], 0, 0, 0);
      o4 = __builtin_amdgcn_mfma_f32_16x16x32_bf16(vone.b8, bp.b8, o4, 0, 0, 0);
    }
    __builtin_amdgcn_s_setprio(0);
    // ---- rotate: sp <- sc; swap K bases; rotate V bases ----
#pragma unroll
    for (int cg = 0; cg < 4; ++cg) sp[cg] = sc[cg];
    { const char* tk = kread; kread = kdst; kdst = (char*)tk; }
    { unsigned tv = vad0; vad0 = vad1; vad1 = vad2; vad2 = tv; }
    { char* td = vdst0; vdst0 = vdst1; vdst1 = vdst2; vdst2 = td; }
  }

  // ---- epilogue tile 31: softmax(31) on sp + PV(31) from vad0 (Vt[1]) ----
  {
    float t0 = fmaxf(fmaxf(sp[0][0], sp[0][1]), sp[0][2]);
    float t1 = fmaxf(fmaxf(sp[0][3], sp[1][0]), sp[1][1]);
    float t2 = fmaxf(fmaxf(sp[1][2], sp[1][3]), sp[2][0]);
    float t3 = fmaxf(fmaxf(sp[2][1], sp[2][2]), sp[2][3]);
    float t4 = fmaxf(fmaxf(sp[3][0], sp[3][1]), sp[3][2]);
    float t5 = fmaxf(fmaxf(t0, t1), t2);
    float t6 = fmaxf(fmaxf(t3, t4), sp[3][3]);
    float pmax = fmaxf(t5, t6);
    pmax = fmaxf(pmax, __shfl_xor(pmax, 16));
    pmax = fmaxf(pmax, __shfl_xor(pmax, 32));
    if (!__all(pmax <= mrun + 8.0f)) {
      float mnew = fmaxf(mrun, pmax);
      float fac = __builtin_amdgcn_exp2f(mrun - mnew);
#pragma unroll
      for (int mg = 0; mg < 4; ++mg)
#pragma unroll
        for (int r = 0; r < 4; ++r) o[mg][r] *= fac;
#pragma unroll
      for (int r = 0; r < 4; ++r) o4[r] *= fac;
      mrun = mnew;
    }
#pragma unroll
    for (int cg = 0; cg < 4; ++cg)
#pragma unroll
      for (int r = 0; r < 4; ++r)
        sp[cg][r] = __builtin_amdgcn_exp2f(sp[cg][r] - mrun);
#pragma unroll
    for (int ks = 0; ks < 2; ++ks) {
      union { unsigned uu[4]; bf16x8 b8; } bp;
      bp.uu[0] = cvtpk(sp[2 * ks][0], sp[2 * ks][1]);
      bp.uu[1] = cvtpk(sp[2 * ks][2], sp[2 * ks][3]);
      bp.uu[2] = cvtpk(sp[2 * ks + 1][0], sp[2 * ks + 1][1]);
      bp.uu[3] = cvtpk(sp[2 * ks + 1][2], sp[2 * ks + 1][3]);
      uint2 q0, q1, q2, q3, q4, q5, q6, q7;
      if (ks == 0) {
        asm volatile(
            "ds_read_b64_tr_b16 %0, %8 offset:0\n\t"
            "ds_read_b64_tr_b16 %1, %8 offset:512\n\t"
            "ds_read_b64_tr_b16 %2, %8 offset:2048\n\t"
            "ds_read_b64_tr_b16 %3, %8 offset:2560\n\t"
            "ds_read_b64_tr_b16 %4, %8 offset:4096\n\t"
            "ds_read_b64_tr_b16 %5, %8 offset:4608\n\t"
            "ds_read_b64_tr_b16 %6, %8 offset:6144\n\t"
            "ds_read_b64_tr_b16 %7, %8 offset:6656\n\t"
            "s_waitcnt lgkmcnt(0)"
            : "=&v"(q0), "=&v"(q1), "=&v"(q2), "=&v"(q3),
              "=&v"(q4), "=&v"(q5), "=&v"(q6), "=&v"(q7)
            : "v"(vad0));
      } else {
        asm volatile(
            "ds_read_b64_tr_b16 %0, %8 offset:1024\n\t"
            "ds_read_b64_tr_b16 %1, %8 offset:1536\n\t"
            "ds_read_b64_tr_b16 %2, %8 offset:3072\n\t"
            "ds_read_b64_tr_b16 %3, %8 offset:3584\n\t"
            "ds_read_b64_tr_b16 %4, %8 offset:5120\n\t"
            "ds_read_b64_tr_b16 %5, %8 offset:5632\n\t"
            "ds_read_b64_tr_b16 %6, %8 offset:7168\n\t"
            "ds_read_b64_tr_b16 %7, %8 offset:7680\n\t"
            "s_waitcnt lgkmcnt(0)"
            : "=&v"(q0), "=&v"(q1), "=&v"(q2), "=&v"(q3),
              "=&v"(q4), "=&v"(q5), "=&v"(q6), "=&v"(q7)
            : "v"(vad0));
      }
      union { uint2 u2[2]; bf16x8 b8; } av0, av1, av2, av3;
      av0.u2[0] = q0; av0.u2[1] = q1;
      av1.u2[0] = q2; av1.u2[1] = q3;
      av2.u2[0] = q4; av2.u2[1] = q5;
      av3.u2[0] = q6; av3.u2[1] = q7;
      o[0] = __builtin_amdgcn_mfma_f32_16x16x32_bf16(av0.b8, bp.b8, o[0], 0, 0, 0);
      o[1] = __builtin_amdgcn_mfma_f32_16x16x32_bf16(av1.b8, bp.b8, o[1], 0, 0, 0);
      o[2] = __builtin_amdgcn_mfma_f32_16x16x32_bf16(av2.b8, bp.b8, o[2], 0, 0, 0);
      o[3] = __builtin_amdgcn_mfma_f32_16x16x32_bf16(av3.b8, bp.b8, o[3], 0, 0, 0);
      o4 = __builtin_amdgcn_mfma_f32_16x16x32_bf16(vone.b8, bp.b8, o4, 0, 0, 0);
    }
  }
#undef QK_INTO
#undef MASK_APPLY

  // ---- epilogue: O^T regs hold col q=l15, row d=mg*16+l4*4+r; o4 = lsum ----
  const float inv = 1.0f / o4[0];
  const long obase = (rowB + qt * 64 + w * 16 + l15) * DD + h * 64 + l4 * 4;
#pragma unroll
  for (int mg = 0; mg < 4; ++mg) {
    *(unsigned*)&ctx[obase + mg * 16] = cvtpk(o[mg][0] * inv, o[mg][1] * inv);
    *(unsigned*)&ctx[obase + mg * 16 + 2] = cvtpk(o[mg][2] * inv, o[mg][3] * inv);
  }
}

// ---------------- workspace layout (bytes) ----------------
static const size_t OFF_WQKV = 0;          // 2304*768*2  = 3538944
static const size_t OFF_WO = 3538944;      // 768*768*2   = 1179648
static const size_t OFF_W1 = 4718592;      // 2048*768*2  = 3145728
static const size_t OFF_W2 = 7864320;      // 768*2048*2  = 3145728
static const size_t OFF_BQKV = 11010048;   // 2304*4
static const size_t OFF_N = 11019264;      // 4096*768*2  (reused for n2)
static const size_t OFF_QKV = 17310720;    // 4096*2304*2 (reused for h)
static const size_t OFF_CTX = 36185088;    // 4096*768*2
static const size_t OFF_X1 = 42476544;     // 4096*768*4
// total = 55059456 bytes

extern "C" void kernel_launch(void* const* d_in, const int* in_sizes, int n_in,
                              void* d_out, int out_size, void* d_ws, size_t ws_size,
                              hipStream_t stream) {
  (void)in_sizes; (void)n_in; (void)out_size; (void)ws_size;
  const float* x = (const float*)d_in[0];
  const int* mask = (const int*)d_in[1];
  const float* Wq = (const float*)d_in[2];
  const float* bq = (const float*)d_in[3];
  const float* Wk = (const float*)d_in[4];
  const float* bk = (const float*)d_in[5];
  const float* Wv = (const float*)d_in[6];
  const float* bv = (const float*)d_in[7];
  const float* Wo = (const float*)d_in[8];
  const float* bo = (const float*)d_in[9];
  const float* W1 = (const float*)d_in[10];
  const float* b1 = (const float*)d_in[11];
  const float* W2 = (const float*)d_in[12];
  const float* b2 = (const float*)d_in[13];
  const float* alpha = (const float*)d_in[14];
  const float* beta = (const float*)d_in[15];

  char* ws = (char*)d_ws;
  unsigned short* wqkv = (unsigned short*)(ws + OFF_WQKV);
  unsigned short* wo_b = (unsigned short*)(ws + OFF_WO);
  unsigned short* w1_b = (unsigned short*)(ws + OFF_W1);
  unsigned short* w2_b = (unsigned short*)(ws + OFF_W2);
  float* bqkv = (float*)(ws + OFF_BQKV);
  unsigned short* n_b = (unsigned short*)(ws + OFF_N);
  unsigned short* qkv_b = (unsigned short*)(ws + OFF_QKV);
  unsigned short* h_b = qkv_b;  // reuse after attention
  unsigned short* ctx_b = (unsigned short*)(ws + OFF_CTX);
  float* x1_f = (float*)(ws + OFF_X1);
  float* out_f = (float*)d_out;

  // wqkv->bf16 + bias concat + LN1 (1728 cvt + 1 bias + 1024 LN blocks)
  pre_k<<<2753, 256, 0, stream>>>(Wq, Wk, Wv, bq, bk, bv,
                                  x, alpha, beta, wqkv, bqkv, n_b);
  // fused QKV GEMM: [4096,768] x [2304,768]^T -> [4096,2304] bf16, Q pre-scaled
  // 128x96 tiles: grid (24,32) = 768 blocks = exactly 3/CU
  gemm_bt<128, 96, false, false, true, true><<<dim3(24, 32), 256, 0, stream>>>(
      n_b, wqkv, bqkv, nullptr, qkv_b, BSR, QKV_LD, DD);
  // attention (768 blocks) + fused Wo/W1/W2 conversion (228 blocks)
  attn_kernel<<<996, 256, 0, stream>>>(qkv_b, mask, ctx_b,
                                       Wo, W1, W2, wo_b, w1_b, w2_b);
  // Wo GEMM + residual(x) -> x1 fp32 (64x64 tiles: 768 blocks, 3/CU)
  gemm_bt<64, 64, false, true, false, false><<<dim3(12, 64), 256, 0, stream>>>(
      ctx_b, wo_b, bo, x, x1_f, BSR, DD, DD);
  // LN2
  layernorm_k<<<1024, 256, 0, stream>>>(x1_f, alpha, beta, n_b);
  // FFN1 + relu -> h bf16 (64x128 tiles: 1024 blocks, exactly 4/CU)
  gemm_bt<64, 128, true, false, true, false><<<dim3(16, 64), 256, 0, stream>>>(
      n_b, w1_b, b1, nullptr, h_b, BSR, DFFF, DD);
  // FFN2 + residual(x1) -> out fp32 (64x64 tiles: 768 blocks, 3/CU)
  gemm_bt<64, 64, false, true, false, false><<<dim3(12, 64), 256, 0, stream>>>(
      h_b, w2_b, b2, x1_f, out_f, BSR, DD, DFFF);
}

// Round 22
// 131.128 us; speedup vs baseline: 1.0322x; 1.0043x over previous
//
#include <hip/hip_runtime.h>

// EncoderLayer: pre-norm MHA + FFN, B=2 S=2048 D=768 H=12 DFF=2048, fp32 I/O,
// bf16 MFMA internals. Pipeline:
//   pre (wqkv->bf16 + bias concat + LN1), QKV-GEMM(fused, Q pre-scaled, 128x96),
//   flash-attn (pipelined, speculative-exp2 softmax; + 228 fused cvt blocks),
//   Wo-GEMM+res (64x64), LN2, FFN1+relu (64x128), FFN2+res (64x64) -> d_out
// GEMM LDS tiles XOR-swizzled: 0 bank conflicts on ds_read_b128.
#define SS   2048
#define DD   768
#define HH   12
#define DFFF 2048
#define BSR  4096      // B*S
#define QKV_LD 2304

typedef __attribute__((ext_vector_type(8))) short bf16x8;
typedef __attribute__((ext_vector_type(4))) float f32x4;

__device__ __forceinline__ unsigned short f2b(float f) {
  union { float f; unsigned u; } x; x.f = f;
  unsigned r = (x.u + 0x7FFFu + ((x.u >> 16) & 1u)) >> 16;
  return (unsigned short)r;
}

__device__ __forceinline__ unsigned cvtpk(float lo, float hi) {
  unsigned r;
  asm("v_cvt_pk_bf16_f32 %0, %1, %2" : "=v"(r) : "v"(lo), "v"(hi));
  return r;
}

__device__ __forceinline__ void gload_lds16(const void* g, void* l) {
  __builtin_amdgcn_global_load_lds(
      (const __attribute__((address_space(1))) unsigned int*)g,
      (__attribute__((address_space(3))) unsigned int*)l,
      16, 0, 0);
}

// low 32 bits of a flat __shared__ pointer = LDS byte offset on gfx9
__device__ __forceinline__ unsigned lds_u32(const void* p) {
  return (unsigned)(unsigned long long)p;
}

// ---------------- LayerNorm row (torch semantics: ddof=1, eps on std) -------
__device__ __forceinline__ void ln_row(const float* __restrict__ xr,
                                       const float* __restrict__ alpha,
                                       const float* __restrict__ beta,
                                       unsigned short* __restrict__ orow, int lane) {
  float4 v[3];
#pragma unroll
  for (int g = 0; g < 3; ++g) v[g] = *(const float4*)&xr[lane * 12 + g * 4];
  float sum = 0.f;
#pragma unroll
  for (int g = 0; g < 3; ++g) sum += v[g].x + v[g].y + v[g].z + v[g].w;
#pragma unroll
  for (int off = 1; off < 64; off <<= 1) sum += __shfl_xor(sum, off);
  float mu = sum * (1.0f / 768.0f);
  float ss = 0.f;
#pragma unroll
  for (int g = 0; g < 3; ++g) {
    float a0 = v[g].x - mu, a1 = v[g].y - mu, a2 = v[g].z - mu, a3 = v[g].w - mu;
    ss += a0 * a0 + a1 * a1 + a2 * a2 + a3 * a3;
  }
#pragma unroll
  for (int off = 1; off < 64; off <<= 1) ss += __shfl_xor(ss, off);
  float sd = sqrtf(ss * (1.0f / 767.0f));
  float inv = 1.0f / (sd + 1e-6f);
#pragma unroll
  for (int g = 0; g < 3; ++g) {
    float4 al = *(const float4*)&alpha[lane * 12 + g * 4];
    float4 be = *(const float4*)&beta[lane * 12 + g * 4];
    uint2 pk;
    pk.x = cvtpk(al.x * (v[g].x - mu) * inv + be.x, al.y * (v[g].y - mu) * inv + be.y);
    pk.y = cvtpk(al.z * (v[g].z - mu) * inv + be.z, al.w * (v[g].w - mu) * inv + be.w);
    *(uint2*)&orow[lane * 12 + g * 4] = pk;
  }
}

// ------- merged: wqkv fp32->bf16 + bias concat + LN1 (one launch) -----------
__global__ __launch_bounds__(256) void pre_k(const float* __restrict__ Wq,
                                             const float* __restrict__ Wk,
                                             const float* __restrict__ Wv,
                                             const float* __restrict__ bq,
                                             const float* __restrict__ bk,
                                             const float* __restrict__ bv,
                                             const float* __restrict__ x,
                                             const float* __restrict__ alpha,
                                             const float* __restrict__ beta,
                                             unsigned short* __restrict__ wqkv,
                                             float* __restrict__ bqkv,
                                             unsigned short* __restrict__ n_b) {
  const int blk = blockIdx.x;
  if (blk < 1728) {            // Wq/Wk/Wv -> wqkv rows [0,2304)
    int r = blk / 576;
    const float* src = r == 0 ? Wq : r == 1 ? Wk : Wv;
    unsigned short* dst = wqkv + (long)r * 589824;
    long off = (long)(blk - r * 576) * 1024 + threadIdx.x * 4;
    float4 v = *(const float4*)&src[off];
    uint2 pk;
    pk.x = cvtpk(v.x, v.y);
    pk.y = cvtpk(v.z, v.w);
    *(uint2*)&dst[off] = pk;
  } else if (blk == 1728) {    // bias concat
    for (int k = threadIdx.x; k < 2304; k += 256)
      bqkv[k] = k < 768 ? bq[k] : k < 1536 ? bk[k - 768] : bv[k - 1536];
  } else {                     // LN1: 4 rows per block
    int row = (blk - 1729) * 4 + (threadIdx.x >> 6);
    ln_row(x + (long)row * DD, alpha, beta, n_b + (long)row * DD, threadIdx.x & 63);
  }
}

// ---------------- LN2 standalone ----------------
__global__ __launch_bounds__(256) void layernorm_k(const float* __restrict__ x,
                                                   const float* __restrict__ alpha,
                                                   const float* __restrict__ beta,
                                                   unsigned short* __restrict__ outb) {
  int row = blockIdx.x * 4 + (threadIdx.x >> 6);
  ln_row(x + (long)row * DD, alpha, beta, outb + (long)row * DD, threadIdx.x & 63);
}

// ---------------- bf16 GEMM: C[M,N] = A[M,K] * W[N,K]^T (+bias,+res,relu) ----
// BMxBN tile, BK=64, 4 waves (2x2), global_load_lds staging.
// LDS XOR-swizzle: stage source col chunk ^= row&7 (linear LDS dest),
// fragment reads offset ^= (l15&7)<<4 -> conflict-free.
// XCD-chunked block swizzle (requires (gridDim.x*gridDim.y) % 8 == 0).
// QSC: scale cols<768 by 0.125*log2(e) (Q pre-scale for exp2-domain attn).
template <int BM, int BN, bool RELU, bool RES, bool OUTB, bool QSC>
__global__ __launch_bounds__(256, (BM == 64 || BN == 64) ? 4 : 3)
void gemm_bt(const unsigned short* __restrict__ A,
             const unsigned short* __restrict__ W,
             const float* __restrict__ bias,
             const float* __restrict__ res,
             void* __restrict__ outp,
             int M, int N, int K) {
  __shared__ __align__(16) unsigned short As[BM * 64];
  __shared__ __align__(16) unsigned short Bs[BN * 64];
  constexpr int MF = BM / 32;   // 16-wide row frags per wave
  constexpr int NF = BN / 32;   // 16-wide col frags per wave
  const int t = threadIdx.x;
  const int lane = t & 63;
  const int w = t >> 6;
  const int wr = w >> 1, wc = w & 1;
  const int l15 = lane & 15, l4 = lane >> 4;
  // XCD-chunked swizzle: contiguous chunk of blocks (sharing A-panels) per XCD
  const int nwg = gridDim.x * gridDim.y;
  const int lin = blockIdx.y * gridDim.x + blockIdx.x;
  const int u2 = (lin & 7) * (nwg >> 3) + (lin >> 3);
  const long brow = (long)(u2 / gridDim.x) * BM;
  const long bcol = (long)(u2 % gridDim.x) * BN;
  f32x4 acc[MF][NF] = {};
  const int r0 = t >> 3;                       // 0..31 (row within 32-chunk)
  const int c8s = (((t & 7) ^ (r0 & 7)) & 7) * 8;  // swizzled col (shorts)
  const int rd_swz = (l15 & 7) << 4;           // read-side XOR (bytes)

  for (int k0 = 0; k0 < K; k0 += 64) {
    __syncthreads();
#pragma unroll
    for (int p = 0; p < BM / 32; ++p)
      gload_lds16(&A[(brow + p * 32 + r0) * (long)K + k0 + c8s],
                  (char*)As + p * 4096 + w * 1024);
#pragma unroll
    for (int p = 0; p < BN / 32; ++p)
      gload_lds16(&W[(bcol + p * 32 + r0) * (long)K + k0 + c8s],
                  (char*)Bs + p * 4096 + w * 1024);
    __syncthreads();
#pragma unroll
    for (int ks = 0; ks < 2; ++ks) {
      bf16x8 a[MF], b[NF];
#pragma unroll
      for (int m = 0; m < MF; ++m)
        a[m] = *(const bf16x8*)((const char*)As +
                                (wr * (BM / 2) + m * 16 + l15) * 128 +
                                ((ks * 64 + l4 * 16) ^ rd_swz));
#pragma unroll
      for (int n = 0; n < NF; ++n)
        b[n] = *(const bf16x8*)((const char*)Bs +
                                (wc * (BN / 2) + n * 16 + l15) * 128 +
                                ((ks * 64 + l4 * 16) ^ rd_swz));
#pragma unroll
      for (int m = 0; m < MF; ++m)
#pragma unroll
        for (int n = 0; n < NF; ++n)
          acc[m][n] = __builtin_amdgcn_mfma_f32_16x16x32_bf16(a[m], b[n], acc[m][n], 0, 0, 0);
    }
  }
#pragma unroll
  for (int n = 0; n < NF; ++n) {
    const long col = bcol + wc * (BN / 2) + n * 16 + l15;
    const float bv = bias[col];
    const float sc = (QSC && col < 768) ? 0.18033688f : 1.0f;
#pragma unroll
    for (int m = 0; m < MF; ++m) {
      const long row0 = brow + wr * (BM / 2) + m * 16 + l4 * 4;
#pragma unroll
      for (int r = 0; r < 4; ++r) {
        float v = acc[m][n][r] + bv;
        if (RELU) v = fmaxf(v, 0.0f);
        if (QSC) v *= sc;
        long o = (row0 + r) * (long)N + col;
        if (RES) v += res[o];
        if (OUTB) ((unsigned short*)outp)[o] = f2b(v);
        else ((float*)outp)[o] = v;
      }
    }
  }
}

// ---------------- flash attention v15: speculative-exp2 softmax -------------
// Blocks [0,768): one block per (b,h,64-q-tile), 4 waves, 32 KV tiles,
// pipelined QK(i+1) || softmax+PV(i). K: 2 LDS bufs; V: 3 LDS bufs.
// Softmax: exp2(s - mrun_old) issued speculatively (independent of the
// cross-lane max reduce; safe because mrun is seeded with tile-0's max);
// rare defer-max branch corrects p/o/o4 by fac = exp2(mrun_old - mnew).
// tr-read V path, ones-MFMA row-sum, cvt_pk.
// Blocks [768,996): convert Wo/W1/W2 fp32->bf16 under attention.
__global__ __launch_bounds__(256, 4) void attn_kernel(const unsigned short* __restrict__ qkv,
                                                      const int* __restrict__ mask,
                                                      unsigned short* __restrict__ ctx,
                                                      const float* __restrict__ Wo,
                                                      const float* __restrict__ W1,
                                                      const float* __restrict__ W2,
                                                      unsigned short* __restrict__ wo_b,
                                                      unsigned short* __restrict__ w1_b,
                                                      unsigned short* __restrict__ w2_b) {
  if (blockIdx.x >= 768) {     // fused weight conversion (block-uniform branch)
    const long base = (long)(blockIdx.x - 768) * 16384 + threadIdx.x * 4;
#pragma unroll 4
    for (int i = 0; i < 16; ++i) {
      long e = base + i * 1024;
      const float* s;
      unsigned short* d;
      long off;
      if (e < 589824) { s = Wo; d = wo_b; off = e; }
      else if (e < 2162688) { s = W1; d = w1_b; off = e - 589824; }
      else { s = W2; d = w2_b; off = e - 2162688; }
      float4 v = *(const float4*)&s[off];
      uint2 pk;
      pk.x = cvtpk(v.x, v.y);
      pk.y = cvtpk(v.z, v.w);
      *(uint2*)&d[off] = pk;
    }
    return;
  }

  __shared__ __align__(16) unsigned short Ks[2][64 * 64];  // K [key][d], XOR-swz
  __shared__ __align__(16) unsigned short Vt[3][64 * 64];  // V subtiled for tr-read
  const int t = threadIdx.x, lane = t & 63, w = t >> 6;
  const int l15 = lane & 15, l4 = lane >> 4;
  // XCD-chunked swizzle over the 768 attn blocks (768 % 8 == 0, bijective)
  const int u = (blockIdx.x & 7) * 96 + (blockIdx.x >> 3);
  const int qt = u & 31;
  const int h = (u >> 5) % 12;
  const int b = u / 384;
  const long rowB = (long)b * SS;

  // ---- mask bitmap (scratch aliased onto Vt[0]; staged only later) ----
  unsigned bm;
  {
    int* tfl = (int*)&Vt[0][0];
    const int* mb = &mask[b * SS + t * 8];
    int4 a0 = *(const int4*)mb;
    int4 a1 = *(const int4*)(mb + 4);
    int allv = (a0.x && a0.y && a0.z && a0.w && a1.x && a1.y && a1.z && a1.w) ? 1 : 0;
    allv &= __shfl_xor(allv, 1);
    allv &= __shfl_xor(allv, 2);
    allv &= __shfl_xor(allv, 4);
    if ((t & 7) == 0) tfl[t >> 3] = allv;
    __syncthreads();
    int vv = (lane < 32) ? tfl[lane] : 1;
    bm = (unsigned)__ballot(vv);   // per-wave; bit kb = tile kb fully unmasked
    __syncthreads();               // scratch dead before Vt[0] is staged
  }

  // Q fragment (B operand): lane l15 = q, elems d = ks*32 + l4*8 + j
  bf16x8 aq[2];
#pragma unroll
  for (int ks = 0; ks < 2; ++ks)
    aq[ks] = *(const bf16x8*)&qkv[(rowB + qt * 64 + w * 16 + l15) * QKV_LD +
                                  h * 64 + ks * 32 + l4 * 8];

  // K staging (gload_lds linear dest; XOR swizzle folded into global src col)
  const int krow = w * 8 + (lane >> 3);                          // +p*32
  const int kdo = (((lane & 7) ^ (lane >> 3)) & 7) << 3;         // shorts
  const unsigned short* kgbase = &qkv[(rowB + krow) * QKV_LD + 768 + h * 64 + kdo];
  const int kread_swz = (l15 & 7) << 4;

  // V staging: decode linear dest X = p*4096 + w*1024 + lane*16 into (key, d0)
  const unsigned short* vsrc[2];
#pragma unroll
  for (int p = 0; p < 2; ++p) {
    int X = p * 4096 + w * 1024 + lane * 16;
    int d_blk = X >> 11;
    int rem = X & 2047;
    int k_blk = rem >> 7;
    int krw = (rem >> 5) & 3;
    int c = (rem >> 4) & 1;
    int vkey = k_blk * 4 + krw;
    int vd0 = d_blk * 16 + c * 8;
    vsrc[p] = &qkv[(rowB + vkey) * QKV_LD + 1536 + h * 64 + vd0];
  }
  // tr-read per-lane address part; rotating V read bases (i%3: 0,1,2,...)
  const unsigned vtrl = (unsigned)(l15 * 2 + l4 * 128);
  unsigned vad0 = lds_u32(&Vt[0][0]) + vtrl;
  unsigned vad1 = lds_u32(&Vt[1][0]) + vtrl;
  unsigned vad2 = lds_u32(&Vt[2][0]) + vtrl;
  // rotating V stage-dest bases ((i+2)%3: 2,0,1,...)
  char* vdst0 = (char*)&Vt[2][0];
  char* vdst1 = (char*)&Vt[0][0];
  char* vdst2 = (char*)&Vt[1][0];
  // K read/stage bases (QK(i+1) reads parity (i+1)&1; stage(i+2) -> parity i&1)
  const char* kread = (const char*)&Ks[1][0];
  char* kdst = (char*)&Ks[0][0];

  // ones A-operand for row-sum MFMA (bf16 1.0 = 0x3F80)
  union { unsigned uu[4]; bf16x8 b8; } vone;
  vone.uu[0] = vone.uu[1] = vone.uu[2] = vone.uu[3] = 0x3F803F80u;

  f32x4 o[4] = {};
  f32x4 o4 = {};                 // row-sum accumulator (all regs = sum for q=l15)
  float mrun;                    // seeded from tile 0's max below
  f32x4 sp[4];                   // scores of tile i (being softmaxed/PV'd)

#define QK_INTO(dst, kbase)                                                     \
  { __builtin_amdgcn_s_setprio(1);                                             \
    _Pragma("unroll") for (int ks = 0; ks < 2; ++ks)                           \
    _Pragma("unroll") for (int cg = 0; cg < 4; ++cg) {                         \
      bf16x8 ak = *(const bf16x8*)((kbase) + (cg * 16 + l15) * 128 +           \
                                   ((ks * 64 + l4 * 16) ^ kread_swz));         \
      dst[cg] = __builtin_amdgcn_mfma_f32_16x16x32_bf16(ak, aq[ks], dst[cg], 0, 0, 0); \
    }                                                                           \
    __builtin_amdgcn_s_setprio(0); }

#define MASK_APPLY(dst, kb)                                                     \
  if (__builtin_expect(!((bm >> (kb)) & 1), 0)) {                              \
    const int* mb2 = &mask[b * SS + (kb) * 64 + l4 * 4];                       \
    _Pragma("unroll") for (int cg = 0; cg < 4; ++cg) {                         \
      int4 mm = *(const int4*)(mb2 + cg * 16);                                 \
      int mi[4] = {mm.x, mm.y, mm.z, mm.w};                                    \
      _Pragma("unroll") for (int r = 0; r < 4; ++r)                            \
        dst[cg][r] += mi[r] ? 0.f : -1.44269504e9f;                            \
    } }

#define MAXTREE(src, out)                                                       \
  { float t0 = fmaxf(fmaxf(src[0][0], src[0][1]), src[0][2]);                  \
    float t1 = fmaxf(fmaxf(src[0][3], src[1][0]), src[1][1]);                  \
    float t2 = fmaxf(fmaxf(src[1][2], src[1][3]), src[2][0]);                  \
    float t3 = fmaxf(fmaxf(src[2][1], src[2][2]), src[2][3]);                  \
    float t4 = fmaxf(fmaxf(src[3][0], src[3][1]), src[3][2]);                  \
    float t5 = fmaxf(fmaxf(t0, t1), t2);                                       \
    float t6 = fmaxf(fmaxf(t3, t4), src[3][3]);                                \
    out = fmaxf(t5, t6);                                                       \
    out = fmaxf(out, __shfl_xor(out, 16));                                     \
    out = fmaxf(out, __shfl_xor(out, 32)); }

  // Speculative softmax: exp2(s - mrun) issues independent of the max reduce;
  // rare branch (pmax > mrun + 8) corrects p/o/o4 by fac. Exact.
#define SOFTMAX_SPEC(spv)                                                       \
  { f32x4 pe0 = spv[0], pe1 = spv[1], pe2 = spv[2], pe3 = spv[3];               \
    _Pragma("unroll") for (int r = 0; r < 4; ++r) {                            \
      pe0[r] = __builtin_amdgcn_exp2f(pe0[r] - mrun);                          \
      pe1[r] = __builtin_amdgcn_exp2f(pe1[r] - mrun);                          \
      pe2[r] = __builtin_amdgcn_exp2f(pe2[r] - mrun);                          \
      pe3[r] = __builtin_amdgcn_exp2f(pe3[r] - mrun);                          \
    }                                                                           \
    float pmax;                                                                \
    MAXTREE(spv, pmax);                                                        \
    if (!__all(pmax <= mrun + 8.0f)) {                                         \
      float mnew = fmaxf(mrun, pmax);                                          \
      float fac = __builtin_amdgcn_exp2f(mrun - mnew);                         \
      _Pragma("unroll") for (int mg = 0; mg < 4; ++mg)                         \
      _Pragma("unroll") for (int r = 0; r < 4; ++r) o[mg][r] *= fac;           \
      _Pragma("unroll") for (int r = 0; r < 4; ++r) {                          \
        o4[r] *= fac;                                                          \
        pe0[r] *= fac; pe1[r] *= fac; pe2[r] *= fac; pe3[r] *= fac;            \
      }                                                                         \
      mrun = mnew;                                                             \
    }                                                                           \
    spv[0] = pe0; spv[1] = pe1; spv[2] = pe2; spv[3] = pe3; }

  // ---- prologue: stage tile 0, drain, issue stage tile 1, QK(0) ----
#pragma unroll
  for (int p = 0; p < 2; ++p)
    gload_lds16(kgbase + (long)p * 32 * QKV_LD, (char*)&Ks[0][0] + p * 4096 + w * 1024);
#pragma unroll
  for (int p = 0; p < 2; ++p)
    gload_lds16(vsrc[p], (char*)&Vt[0][0] + p * 4096 + w * 1024);
  __syncthreads();
#pragma unroll
  for (int p = 0; p < 2; ++p)
    gload_lds16(kgbase + ((long)64 + p * 32) * QKV_LD, (char*)&Ks[1][0] + p * 4096 + w * 1024);
#pragma unroll
  for (int p = 0; p < 2; ++p)
    gload_lds16(vsrc[p] + (long)64 * QKV_LD, (char*)&Vt[1][0] + p * 4096 + w * 1024);
#pragma unroll
  for (int cg = 0; cg < 4; ++cg) sp[cg] = f32x4{0.f, 0.f, 0.f, 0.f};
  QK_INTO(sp, (const char*)&Ks[0][0]);
  MASK_APPLY(sp, 0);
  MAXTREE(sp, mrun);   // seed running max from tile 0 (enables speculation)

  for (int i = 0; i < 31; ++i) {
    __syncthreads();   // stage(i+1) landed; all QK(i) reads of Ks done
    // ---- issue stage(i+2): K -> kdst (parity i&1), V -> vdst0 ((i+2)%3) ----
    if (i < 30) {
#pragma unroll
      for (int p = 0; p < 2; ++p)
        gload_lds16(kgbase + ((long)(i + 2) * 64 + p * 32) * QKV_LD,
                    kdst + p * 4096 + w * 1024);
#pragma unroll
      for (int p = 0; p < 2; ++p)
        gload_lds16(vsrc[p] + (long)(i + 2) * 64 * QKV_LD,
                    vdst0 + p * 4096 + w * 1024);
    }
    // ---- QK(i+1) from kread (MFMA pipe; overlaps softmax(i) below) ----
    f32x4 sc[4] = {};
    QK_INTO(sc, kread);
    MASK_APPLY(sc, i + 1);
    // ---- softmax(i) on sp: speculative exp2 || max reduce ----
    SOFTMAX_SPEC(sp);
    // ---- PV(i): bp from sp, av via tr-reads of V[i%3] (vad0) ----
    __builtin_amdgcn_s_setprio(1);
#pragma unroll
    for (int ks = 0; ks < 2; ++ks) {
      union { unsigned uu[4]; bf16x8 b8; } bp;
      bp.uu[0] = cvtpk(sp[2 * ks][0], sp[2 * ks][1]);
      bp.uu[1] = cvtpk(sp[2 * ks][2], sp[2 * ks][3]);
      bp.uu[2] = cvtpk(sp[2 * ks + 1][0], sp[2 * ks + 1][1]);
      bp.uu[3] = cvtpk(sp[2 * ks + 1][2], sp[2 * ks + 1][3]);
      uint2 q0, q1, q2, q3, q4, q5, q6, q7;
      if (ks == 0) {
        asm volatile(
            "ds_read_b64_tr_b16 %0, %8 offset:0\n\t"
            "ds_read_b64_tr_b16 %1, %8 offset:512\n\t"
            "ds_read_b64_tr_b16 %2, %8 offset:2048\n\t"
            "ds_read_b64_tr_b16 %3, %8 offset:2560\n\t"
            "ds_read_b64_tr_b16 %4, %8 offset:4096\n\t"
            "ds_read_b64_tr_b16 %5, %8 offset:4608\n\t"
            "ds_read_b64_tr_b16 %6, %8 offset:6144\n\t"
            "ds_read_b64_tr_b16 %7, %8 offset:6656\n\t"
            "s_waitcnt lgkmcnt(0)"
            : "=&v"(q0), "=&v"(q1), "=&v"(q2), "=&v"(q3),
              "=&v"(q4), "=&v"(q5), "=&v"(q6), "=&v"(q7)
            : "v"(vad0));
      } else {
        asm volatile(
            "ds_read_b64_tr_b16 %0, %8 offset:1024\n\t"
            "ds_read_b64_tr_b16 %1, %8 offset:1536\n\t"
            "ds_read_b64_tr_b16 %2, %8 offset:3072\n\t"
            "ds_read_b64_tr_b16 %3, %8 offset:3584\n\t"
            "ds_read_b64_tr_b16 %4, %8 offset:5120\n\t"
            "ds_read_b64_tr_b16 %5, %8 offset:5632\n\t"
            "ds_read_b64_tr_b16 %6, %8 offset:7168\n\t"
            "ds_read_b64_tr_b16 %7, %8 offset:7680\n\t"
            "s_waitcnt lgkmcnt(0)"
            : "=&v"(q0), "=&v"(q1), "=&v"(q2), "=&v"(q3),
              "=&v"(q4), "=&v"(q5), "=&v"(q6), "=&v"(q7)
            : "v"(vad0));
      }
      union { uint2 u2[2]; bf16x8 b8; } av0, av1, av2, av3;
      av0.u2[0] = q0; av0.u2[1] = q1;
      av1.u2[0] = q2; av1.u2[1] = q3;
      av2.u2[0] = q4; av2.u2[1] = q5;
      av3.u2[0] = q6; av3.u2[1] = q7;
      o[0] = __builtin_amdgcn_mfma_f32_16x16x32_bf16(av0.b8, bp.b8, o[0], 0, 0, 0);
      o[1] = __builtin_amdgcn_mfma_f32_16x16x32_bf16(av1.b8, bp.b8, o[1], 0, 0, 0);
      o[2] = __builtin_amdgcn_mfma_f32_16x16x32_bf16(av2.b8, bp.b8, o[2], 0, 0, 0);
      o[3] = __builtin_amdgcn_mfma_f32_16x16x32_bf16(av3.b8, bp.b8, o[3], 0, 0, 0);
      o4 = __builtin_amdgcn_mfma_f32_16x16x32_bf16(vone.b8, bp.b8, o4, 0, 0, 0);
    }
    __builtin_amdgcn_s_setprio(0);
    // ---- rotate: sp <- sc; swap K bases; rotate V bases ----
#pragma unroll
    for (int cg = 0; cg < 4; ++cg) sp[cg] = sc[cg];
    { const char* tk = kread; kread = kdst; kdst = (char*)tk; }
    { unsigned tv = vad0; vad0 = vad1; vad1 = vad2; vad2 = tv; }
    { char* td = vdst0; vdst0 = vdst1; vdst1 = vdst2; vdst2 = td; }
  }

  // ---- epilogue tile 31: softmax(31) on sp + PV(31) from vad0 (Vt[1]) ----
  {
    SOFTMAX_SPEC(sp);
#pragma unroll
    for (int ks = 0; ks < 2; ++ks) {
      union { unsigned uu[4]; bf16x8 b8; } bp;
      bp.uu[0] = cvtpk(sp[2 * ks][0], sp[2 * ks][1]);
      bp.uu[1] = cvtpk(sp[2 * ks][2], sp[2 * ks][3]);
      bp.uu[2] = cvtpk(sp[2 * ks + 1][0], sp[2 * ks + 1][1]);
      bp.uu[3] = cvtpk(sp[2 * ks + 1][2], sp[2 * ks + 1][3]);
      uint2 q0, q1, q2, q3, q4, q5, q6, q7;
      if (ks == 0) {
        asm volatile(
            "ds_read_b64_tr_b16 %0, %8 offset:0\n\t"
            "ds_read_b64_tr_b16 %1, %8 offset:512\n\t"
            "ds_read_b64_tr_b16 %2, %8 offset:2048\n\t"
            "ds_read_b64_tr_b16 %3, %8 offset:2560\n\t"
            "ds_read_b64_tr_b16 %4, %8 offset:4096\n\t"
            "ds_read_b64_tr_b16 %5, %8 offset:4608\n\t"
            "ds_read_b64_tr_b16 %6, %8 offset:6144\n\t"
            "ds_read_b64_tr_b16 %7, %8 offset:6656\n\t"
            "s_waitcnt lgkmcnt(0)"
            : "=&v"(q0), "=&v"(q1), "=&v"(q2), "=&v"(q3),
              "=&v"(q4), "=&v"(q5), "=&v"(q6), "=&v"(q7)
            : "v"(vad0));
      } else {
        asm volatile(
            "ds_read_b64_tr_b16 %0, %8 offset:1024\n\t"
            "ds_read_b64_tr_b16 %1, %8 offset:1536\n\t"
            "ds_read_b64_tr_b16 %2, %8 offset:3072\n\t"
            "ds_read_b64_tr_b16 %3, %8 offset:3584\n\t"
            "ds_read_b64_tr_b16 %4, %8 offset:5120\n\t"
            "ds_read_b64_tr_b16 %5, %8 offset:5632\n\t"
            "ds_read_b64_tr_b16 %6, %8 offset:7168\n\t"
            "ds_read_b64_tr_b16 %7, %8 offset:7680\n\t"
            "s_waitcnt lgkmcnt(0)"
            : "=&v"(q0), "=&v"(q1), "=&v"(q2), "=&v"(q3),
              "=&v"(q4), "=&v"(q5), "=&v"(q6), "=&v"(q7)
            : "v"(vad0));
      }
      union { uint2 u2[2]; bf16x8 b8; } av0, av1, av2, av3;
      av0.u2[0] = q0; av0.u2[1] = q1;
      av1.u2[0] = q2; av1.u2[1] = q3;
      av2.u2[0] = q4; av2.u2[1] = q5;
      av3.u2[0] = q6; av3.u2[1] = q7;
      o[0] = __builtin_amdgcn_mfma_f32_16x16x32_bf16(av0.b8, bp.b8, o[0], 0, 0, 0);
      o[1] = __builtin_amdgcn_mfma_f32_16x16x32_bf16(av1.b8, bp.b8, o[1], 0, 0, 0);
      o[2] = __builtin_amdgcn_mfma_f32_16x16x32_bf16(av2.b8, bp.b8, o[2], 0, 0, 0);
      o[3] = __builtin_amdgcn_mfma_f32_16x16x32_bf16(av3.b8, bp.b8, o[3], 0, 0, 0);
      o4 = __builtin_amdgcn_mfma_f32_16x16x32_bf16(vone.b8, bp.b8, o4, 0, 0, 0);
    }
  }
#undef QK_INTO
#undef MASK_APPLY
#undef MAXTREE
#undef SOFTMAX_SPEC

  // ---- epilogue: O^T regs hold col q=l15, row d=mg*16+l4*4+r; o4 = lsum ----
  const float inv = 1.0f / o4[0];
  const long obase = (rowB + qt * 64 + w * 16 + l15) * DD + h * 64 + l4 * 4;
#pragma unroll
  for (int mg = 0; mg < 4; ++mg) {
    *(unsigned*)&ctx[obase + mg * 16] = cvtpk(o[mg][0] * inv, o[mg][1] * inv);
    *(unsigned*)&ctx[obase + mg * 16 + 2] = cvtpk(o[mg][2] * inv, o[mg][3] * inv);
  }
}

// ---------------- workspace layout (bytes) ----------------
static const size_t OFF_WQKV = 0;          // 2304*768*2  = 3538944
static const size_t OFF_WO = 3538944;      // 768*768*2   = 1179648
static const size_t OFF_W1 = 4718592;      // 2048*768*2  = 3145728
static const size_t OFF_W2 = 7864320;      // 768*2048*2  = 3145728
static const size_t OFF_BQKV = 11010048;   // 2304*4
static const size_t OFF_N = 11019264;      // 4096*768*2  (reused for n2)
static const size_t OFF_QKV = 17310720;    // 4096*2304*2 (reused for h)
static const size_t OFF_CTX = 36185088;    // 4096*768*2
static const size_t OFF_X1 = 42476544;     // 4096*768*4
// total = 55059456 bytes

extern "C" void kernel_launch(void* const* d_in, const int* in_sizes, int n_in,
                              void* d_out, int out_size, void* d_ws, size_t ws_size,
                              hipStream_t stream) {
  (void)in_sizes; (void)n_in; (void)out_size; (void)ws_size;
  const float* x = (const float*)d_in[0];
  const int* mask = (const int*)d_in[1];
  const float* Wq = (const float*)d_in[2];
  const float* bq = (const float*)d_in[3];
  const float* Wk = (const float*)d_in[4];
  const float* bk = (const float*)d_in[5];
  const float* Wv = (const float*)d_in[6];
  const float* bv = (const float*)d_in[7];
  const float* Wo = (const float*)d_in[8];
  const float* bo = (const float*)d_in[9];
  const float* W1 = (const float*)d_in[10];
  const float* b1 = (const float*)d_in[11];
  const float* W2 = (const float*)d_in[12];
  const float* b2 = (const float*)d_in[13];
  const float* alpha = (const float*)d_in[14];
  const float* beta = (const float*)d_in[15];

  char* ws = (char*)d_ws;
  unsigned short* wqkv = (unsigned short*)(ws + OFF_WQKV);
  unsigned short* wo_b = (unsigned short*)(ws + OFF_WO);
  unsigned short* w1_b = (unsigned short*)(ws + OFF_W1);
  unsigned short* w2_b = (unsigned short*)(ws + OFF_W2);
  float* bqkv = (float*)(ws + OFF_BQKV);
  unsigned short* n_b = (unsigned short*)(ws + OFF_N);
  unsigned short* qkv_b = (unsigned short*)(ws + OFF_QKV);
  unsigned short* h_b = qkv_b;  // reuse after attention
  unsigned short* ctx_b = (unsigned short*)(ws + OFF_CTX);
  float* x1_f = (float*)(ws + OFF_X1);
  float* out_f = (float*)d_out;

  // wqkv->bf16 + bias concat + LN1 (1728 cvt + 1 bias + 1024 LN blocks)
  pre_k<<<2753, 256, 0, stream>>>(Wq, Wk, Wv, bq, bk, bv,
                                  x, alpha, beta, wqkv, bqkv, n_b);
  // fused QKV GEMM: [4096,768] x [2304,768]^T -> [4096,2304] bf16, Q pre-scaled
  // 128x96 tiles: grid (24,32) = 768 blocks = exactly 3/CU
  gemm_bt<128, 96, false, false, true, true><<<dim3(24, 32), 256, 0, stream>>>(
      n_b, wqkv, bqkv, nullptr, qkv_b, BSR, QKV_LD, DD);
  // attention (768 blocks) + fused Wo/W1/W2 conversion (228 blocks)
  attn_kernel<<<996, 256, 0, stream>>>(qkv_b, mask, ctx_b,
                                       Wo, W1, W2, wo_b, w1_b, w2_b);
  // Wo GEMM + residual(x) -> x1 fp32 (64x64 tiles: 768 blocks, 3/CU)
  gemm_bt<64, 64, false, true, false, false><<<dim3(12, 64), 256, 0, stream>>>(
      ctx_b, wo_b, bo, x, x1_f, BSR, DD, DD);
  // LN2
  layernorm_k<<<1024, 256, 0, stream>>>(x1_f, alpha, beta, n_b);
  // FFN1 + relu -> h bf16 (64x128 tiles: 1024 blocks, exactly 4/CU)
  gemm_bt<64, 128, true, false, true, false><<<dim3(16, 64), 256, 0, stream>>>(
      n_b, w1_b, b1, nullptr, h_b, BSR, DFFF, DD);
  // FFN2 + residual(x1) -> out fp32 (64x64 tiles: 768 blocks, 3/CU)
  gemm_bt<64, 64, false, true, false, false><<<dim3(12, 64), 256, 0, stream>>>(
      h_b, w2_b, b2, x1_f, out_f, BSR, DD, DFFF);
}